// Round 1
// baseline (387.468 us; speedup 1.0000x reference)
//
#include <hip/hip_runtime.h>
#include <cstdint>
#include <cstddef>

// ---------------------------------------------------------------------------
// FlashSparseAttention: X->QKV proj -> RoPE -> causal GQA flash attn -> O proj
// B=2 S=2048 H=2048 NH=16 NKV=4 HD=128, fp32 in/out, bf16 MFMA internally.
// ---------------------------------------------------------------------------

typedef __bf16 bf16x8 __attribute__((ext_vector_type(8)));
typedef float f32x4 __attribute__((ext_vector_type(4)));

#define DEVFN static __device__ __forceinline__

constexpr int Bc = 2, Sc = 2048, Hc = 2048, NHc = 16, NKVc = 4, HDc = 128;
constexpr int TOKc = Bc * Sc;  // 4096
constexpr float SM_SCALE = 0.08838834764831845f;  // 1/sqrt(128)
constexpr float LOG2E = 1.4426950408889634f;

DEVFN unsigned short f2bf(float f) {
  unsigned u = __float_as_uint(f);
  u += 0x7fffu + ((u >> 16) & 1u);  // RNE
  return (unsigned short)(u >> 16);
}
DEVFN float bf2f(unsigned short s) { return __uint_as_float(((unsigned)s) << 16); }

DEVFN void gload_lds16(const void* g, void* l) {
  __builtin_amdgcn_global_load_lds(
      (const __attribute__((address_space(1))) unsigned int*)g,
      (__attribute__((address_space(3))) unsigned int*)l, 16, 0, 0);
}

// ---------------- fp32 -> bf16 conversion (vectorized x4) ------------------
__global__ __launch_bounds__(256) void cvt_kernel(const float* __restrict__ in,
                                                  unsigned short* __restrict__ out,
                                                  int n4) {
  int i = blockIdx.x * 256 + threadIdx.x;
  if (i >= n4) return;
  float4 v = reinterpret_cast<const float4*>(in)[i];
  ushort4 o;
  o.x = f2bf(v.x); o.y = f2bf(v.y); o.z = f2bf(v.z); o.w = f2bf(v.w);
  reinterpret_cast<ushort4*>(out)[i] = o;
}

// ---------------- NT GEMM: C[M][N] = A[M][K] * W[N][K]^T  (bf16 MFMA) ------
// 128x128 tile, BK=64, 4 waves (2x2), 4x4 16x16x32 frags/wave (m97 structure)
// MODE 0: bf16 row-major out; MODE 1: f32 row-major out;
// MODE 2: bf16 scatter to Vt[b][kv][d][s] (row=token=(b,s), col=(kv,d))
template <int MODE>
__global__ __launch_bounds__(256) void gemm_bt(const unsigned short* __restrict__ A,
                                               const unsigned short* __restrict__ Bw,
                                               void* __restrict__ Cout, int N, int K) {
  __shared__ __align__(16) unsigned short As[128 * 64];
  __shared__ __align__(16) unsigned short Bs[128 * 64];
  const int tid = threadIdx.x;
  const int w = tid >> 6, l = tid & 63;
  const int ntiles = N >> 7;
  const int bm = (blockIdx.x / ntiles) << 7;
  const int bn = (blockIdx.x % ntiles) << 7;
  const int wm = (w >> 1) << 6;
  const int wn = (w & 1) << 6;

  f32x4 zero4 = {0.f, 0.f, 0.f, 0.f};
  f32x4 acc[4][4];
#pragma unroll
  for (int i = 0; i < 4; i++)
#pragma unroll
    for (int j = 0; j < 4; j++) acc[i][j] = zero4;

  const int srow = w * 8 + (l >> 3);  // row within 32-row staging chunk
  const int scol = (l & 7) * 16;      // byte col within 128B row
  const unsigned short* Ag = A + (size_t)(bm + srow) * K;
  const unsigned short* Bg = Bw + (size_t)(bn + srow) * K;

  for (int kt = 0; kt < K; kt += 64) {
#pragma unroll
    for (int it = 0; it < 4; it++)
      gload_lds16((const char*)(Ag + (size_t)(it * 32) * K + kt) + scol,
                  As + (it * 32 + w * 8) * 64);
#pragma unroll
    for (int it = 0; it < 4; it++)
      gload_lds16((const char*)(Bg + (size_t)(it * 32) * K + kt) + scol,
                  Bs + (it * 32 + w * 8) * 64);
    __syncthreads();
#pragma unroll
    for (int kk = 0; kk < 2; kk++) {
      bf16x8 af[4], bfv[4];
#pragma unroll
      for (int i = 0; i < 4; i++)
        af[i] = *reinterpret_cast<const bf16x8*>(As + (wm + i * 16 + (l & 15)) * 64 +
                                                 kk * 32 + ((l >> 4) << 3));
#pragma unroll
      for (int j = 0; j < 4; j++)
        bfv[j] = *reinterpret_cast<const bf16x8*>(Bs + (wn + j * 16 + (l & 15)) * 64 +
                                                  kk * 32 + ((l >> 4) << 3));
#pragma unroll
      for (int i = 0; i < 4; i++)
#pragma unroll
        for (int j = 0; j < 4; j++)
          acc[i][j] = __builtin_amdgcn_mfma_f32_16x16x32_bf16(af[i], bfv[j], acc[i][j], 0, 0, 0);
    }
    __syncthreads();
  }

  // epilogue: D row = (l>>4)*4 + r, col = l&15 (m89-verified layout)
#pragma unroll
  for (int i = 0; i < 4; i++) {
#pragma unroll
    for (int j = 0; j < 4; j++) {
#pragma unroll
      for (int r = 0; r < 4; r++) {
        const int row = bm + wm + i * 16 + ((l >> 4) << 2) + r;
        const int col = bn + wn + j * 16 + (l & 15);
        const float v = acc[i][j][r];
        if (MODE == 0) {
          ((unsigned short*)Cout)[(size_t)row * N + col] = f2bf(v);
        } else if (MODE == 1) {
          ((float*)Cout)[(size_t)row * N + col] = v;
        } else {
          const int b_ = row >> 11, s_ = row & 2047;
          const int kvh = col >> 7, d = col & 127;
          ((unsigned short*)Cout)[((size_t)((b_ * NKVc + kvh) * HDc + d) << 11) + s_] = f2bf(v);
        }
      }
    }
  }
}

// ---------------- RoPE + relayout: raw[token][h*128+d] -> dst[b][h][s][d] --
template <int NHEADS, bool SCALE>
__global__ __launch_bounds__(256) void rope_kernel(const unsigned short* __restrict__ raw,
                                                   unsigned short* __restrict__ dst) {
  const int t = blockIdx.x * 256 + threadIdx.x;
  const int d = t & 63;
  const int h = (t >> 6) & (NHEADS - 1);
  const int tok = t / (64 * NHEADS);
  const int b = tok >> 11, s = tok & 2047;
  const float inv = exp2f(-0.2076205059304601f * (float)d);  // 10000^(-d/64)
  const float ang = (float)s * inv;
  float sn, c;
  sincosf(ang, &sn, &c);
  const size_t src = (size_t)tok * (NHEADS * 128) + h * 128 + d;
  const float x0 = bf2f(raw[src]);
  const float x1 = bf2f(raw[src + 64]);
  float o0 = x0 * c - x1 * sn;
  float o1 = x1 * c + x0 * sn;
  if (SCALE) { o0 *= SM_SCALE; o1 *= SM_SCALE; }
  const size_t db = ((size_t)(b * NHEADS + h) * Sc + s) * HDc + d;
  dst[db] = f2bf(o0);
  dst[db + 64] = f2bf(o1);
}

// ---------------- causal GQA flash attention -------------------------------
// grid: (B*NH)*32 blocks; block = 4 waves; Q tile 64 rows (16/wave); KV tile 64.
// Q pre-scaled by 1/sqrt(HD). K_lds/V_lds XOR-swizzled (both-sides, rule #21).
__global__ __launch_bounds__(256) void attn_kernel(const unsigned short* __restrict__ Q,
                                                   const unsigned short* __restrict__ Kr,
                                                   const unsigned short* __restrict__ Vt,
                                                   unsigned short* __restrict__ O) {
  __shared__ __align__(16) unsigned short Ks[64 * 128];   // [kv][d] swizzled
  __shared__ __align__(16) unsigned short Vs[128 * 64];   // [d][kv] swizzled
  __shared__ __align__(16) unsigned short Ps[4][16 * 64]; // per-wave P

  const int tid = threadIdx.x, w = tid >> 6, l = tid & 63;
  const int qt = blockIdx.x & 31, bh = blockIdx.x >> 5;
  const int b = bh >> 4, h = bh & 15, kvh = h >> 2;
  const int q0 = qt << 6;

  // Q A-fragments (rows q0+w*16+(l&15), k = kk*32+8*(l>>4)..+7), kept in regs
  const unsigned short* Qb =
      Q + ((size_t)bh * Sc + q0 + w * 16 + (l & 15)) * HDc + ((l >> 4) << 3);
  bf16x8 qf[4];
#pragma unroll
  for (int kk = 0; kk < 4; kk++)
    qf[kk] = *reinterpret_cast<const bf16x8*>(Qb + kk * 32);

  f32x4 zero4 = {0.f, 0.f, 0.f, 0.f};
  f32x4 oacc[8];
#pragma unroll
  for (int i = 0; i < 8; i++) oacc[i] = zero4;
  float mrow[4] = {-1e30f, -1e30f, -1e30f, -1e30f};
  float sume[4] = {0.f, 0.f, 0.f, 0.f};

  const unsigned short* Kb = Kr + (size_t)(b * NKVc + kvh) * Sc * HDc;
  const unsigned short* Vb = Vt + (size_t)(b * NKVc + kvh) * HDc * Sc;

  // staging: K 16 rows/issue (256B rows), V 32 rows/issue (128B rows)
  const int krow = w * 4 + (l >> 4);
  const int kcb = ((l & 15) * 16) ^ ((krow & 7) << 4);  // pre-swizzled source col
  const int vrow = w * 8 + (l >> 3);
  const int vcb = ((l & 7) * 16) ^ ((vrow & 7) << 4);

  for (int kt = 0; kt <= qt; kt++) {
    __syncthreads();  // prev tile fully consumed before overwrite
#pragma unroll
    for (int it = 0; it < 4; it++)
      gload_lds16((const char*)(Kb + (size_t)(kt * 64 + it * 16 + krow) * HDc) + kcb,
                  Ks + (it * 16 + w * 4) * 128);
#pragma unroll
    for (int it = 0; it < 4; it++)
      gload_lds16((const char*)(Vb + (size_t)(it * 32 + vrow) * Sc + kt * 64) + vcb,
                  Vs + (it * 32 + w * 8) * 64);
    __syncthreads();

    // S = Q K^T : 4 kv-16 frags x 4 k-chunks
    f32x4 sacc[4];
#pragma unroll
    for (int nf = 0; nf < 4; nf++) sacc[nf] = zero4;
#pragma unroll
    for (int nf = 0; nf < 4; nf++) {
      const int kr = nf * 16 + (l & 15);
#pragma unroll
      for (int kk = 0; kk < 4; kk++) {
        const int cb = (kk * 32 + ((l >> 4) << 3)) * 2;
        bf16x8 kf = *reinterpret_cast<const bf16x8*>((const char*)Ks + kr * 256 +
                                                     (cb ^ ((kr & 7) << 4)));
        sacc[nf] = __builtin_amdgcn_mfma_f32_16x16x32_bf16(qf[kk], kf, sacc[nf], 0, 0, 0);
      }
    }

    if (kt == qt) {  // causal mask on diagonal tile
      const int qg = (w << 4) + ((l >> 4) << 2);
#pragma unroll
      for (int nf = 0; nf < 4; nf++) {
        const int kvl = nf * 16 + (l & 15);
#pragma unroll
        for (int r = 0; r < 4; r++)
          if (kvl > qg + r) sacc[nf][r] = -1e30f;
      }
    }

    // online softmax (row stats per (group,reg); 16-lane shfl reduce)
    float alpha[4];
#pragma unroll
    for (int r = 0; r < 4; r++) {
      float t = fmaxf(fmaxf(sacc[0][r], sacc[1][r]), fmaxf(sacc[2][r], sacc[3][r]));
#pragma unroll
      for (int m = 1; m < 16; m <<= 1) t = fmaxf(t, __shfl_xor(t, m));
      const float mn = fmaxf(mrow[r], t);
      alpha[r] = exp2f((mrow[r] - mn) * LOG2E);
      mrow[r] = mn;
      sume[r] *= alpha[r];
    }
#pragma unroll
    for (int i = 0; i < 8; i++) {
      f32x4 t = oacc[i];
      t[0] *= alpha[0]; t[1] *= alpha[1]; t[2] *= alpha[2]; t[3] *= alpha[3];
      oacc[i] = t;
    }

    unsigned short* Pw = Ps[w];
#pragma unroll
    for (int nf = 0; nf < 4; nf++) {
#pragma unroll
      for (int r = 0; r < 4; r++) {
        const float p = exp2f((sacc[nf][r] - mrow[r]) * LOG2E);
        sume[r] += p;
        Pw[(((l >> 4) << 2) + r) * 64 + nf * 16 + (l & 15)] = f2bf(p);
      }
    }

    // O += P V  (A = P from LDS, B = V^T rows contiguous)
#pragma unroll
    for (int kk = 0; kk < 2; kk++) {
      bf16x8 pf = *reinterpret_cast<const bf16x8*>(Pw + (l & 15) * 64 + kk * 32 +
                                                   ((l >> 4) << 3));
#pragma unroll
      for (int df = 0; df < 8; df++) {
        const int vr = df * 16 + (l & 15);
        const int cb = (kk * 32 + ((l >> 4) << 3)) * 2;
        bf16x8 vf = *reinterpret_cast<const bf16x8*>((const char*)Vs + vr * 128 +
                                                     (cb ^ ((vr & 7) << 4)));
        oacc[df] = __builtin_amdgcn_mfma_f32_16x16x32_bf16(pf, vf, oacc[df], 0, 0, 0);
      }
    }
  }

  float rinv[4];
#pragma unroll
  for (int r = 0; r < 4; r++) {
    float t = sume[r];
#pragma unroll
    for (int m = 1; m < 16; m <<= 1) t += __shfl_xor(t, m);
    rinv[r] = 1.0f / t;
  }
  unsigned short* Ob = O + ((size_t)(b * Sc + q0 + (w << 4) + ((l >> 4) << 2)) * (NHc * HDc)) +
                       h * HDc + (l & 15);
#pragma unroll
  for (int df = 0; df < 8; df++)
#pragma unroll
    for (int r = 0; r < 4; r++)
      Ob[(size_t)r * (NHc * HDc) + df * 16] = f2bf(oacc[df][r] * rinv[r]);
}

// ---------------------------------------------------------------------------
extern "C" void kernel_launch(void* const* d_in, const int* in_sizes, int n_in,
                              void* d_out, int out_size, void* d_ws, size_t ws_size,
                              hipStream_t stream) {
  (void)in_sizes; (void)n_in; (void)out_size; (void)ws_size;
  const float* X = (const float*)d_in[0];
  const float* Wq = (const float*)d_in[1];
  const float* Wk = (const float*)d_in[2];
  const float* Wv = (const float*)d_in[3];
  const float* Wo = (const float*)d_in[4];

  char* ws = (char*)d_ws;
  unsigned short* Xbf = (unsigned short*)(ws + 0);          // 4096x2048
  unsigned short* Wqb = (unsigned short*)(ws + 16777216);   // 2048x2048
  unsigned short* Wkb = (unsigned short*)(ws + 25165824);   // 512x2048
  unsigned short* Wvb = (unsigned short*)(ws + 27262976);   // 512x2048
  unsigned short* Wob = (unsigned short*)(ws + 29360128);   // 2048x2048
  unsigned short* Qraw = (unsigned short*)(ws + 37748736);  // 4096x2048
  unsigned short* Kraw = (unsigned short*)(ws + 54525952);  // 4096x512
  unsigned short* Vt = (unsigned short*)(ws + 58720256);    // [b][kv][d][s]
  unsigned short* Qr = (unsigned short*)(ws + 62914560);    // [b][h][s][d]
  unsigned short* Kr = (unsigned short*)(ws + 79691776);    // [b][kv][s][d]
  unsigned short* Ows = (unsigned short*)(ws + 83886080);   // 4096x2048

  cvt_kernel<<<8192, 256, 0, stream>>>(X, Xbf, 2097152);
  cvt_kernel<<<4096, 256, 0, stream>>>(Wq, Wqb, 1048576);
  cvt_kernel<<<1024, 256, 0, stream>>>(Wk, Wkb, 262144);
  cvt_kernel<<<1024, 256, 0, stream>>>(Wv, Wvb, 262144);
  cvt_kernel<<<4096, 256, 0, stream>>>(Wo, Wob, 1048576);

  gemm_bt<0><<<32 * 16, 256, 0, stream>>>(Xbf, Wqb, Qraw, 2048, 2048);
  gemm_bt<0><<<32 * 4, 256, 0, stream>>>(Xbf, Wkb, Kraw, 512, 2048);
  gemm_bt<2><<<32 * 4, 256, 0, stream>>>(Xbf, Wvb, Vt, 512, 2048);

  rope_kernel<16, true><<<16384, 256, 0, stream>>>(Qraw, Qr);
  rope_kernel<4, false><<<4096, 256, 0, stream>>>(Kraw, Kr);

  attn_kernel<<<1024, 256, 0, stream>>>(Qr, Kr, Vt, Ows);

  gemm_bt<1><<<32 * 16, 256, 0, stream>>>(Ows, Wob, d_out, 2048, 2048);
}

// Round 2
// 314.619 us; speedup vs baseline: 1.2315x; 1.2315x over previous
//
#include <hip/hip_runtime.h>
#include <cstdint>
#include <cstddef>

// ---------------------------------------------------------------------------
// FlashSparseAttention: X->QKV proj -> RoPE -> causal GQA flash attn -> O proj
// B=2 S=2048 H=2048 NH=16 NKV=4 HD=128, fp32 in/out, bf16 MFMA internally.
// R2: attn rewritten — paired q-tiles (perfect load balance, 33 iters/block),
//     double-buffered K/V with counted vmcnt(8) prefetch, P-tile XOR swizzle.
// ---------------------------------------------------------------------------

typedef __bf16 bf16x8 __attribute__((ext_vector_type(8)));
typedef float f32x4 __attribute__((ext_vector_type(4)));

#define DEVFN static __device__ __forceinline__

constexpr int Bc = 2, Sc = 2048, Hc = 2048, NHc = 16, NKVc = 4, HDc = 128;
constexpr float SM_SCALE = 0.08838834764831845f;  // 1/sqrt(128)
constexpr float LOG2E = 1.4426950408889634f;

DEVFN unsigned short f2bf(float f) {
  unsigned u = __float_as_uint(f);
  u += 0x7fffu + ((u >> 16) & 1u);  // RNE
  return (unsigned short)(u >> 16);
}
DEVFN float bf2f(unsigned short s) { return __uint_as_float(((unsigned)s) << 16); }

DEVFN void gload_lds16(const void* g, void* l) {
  __builtin_amdgcn_global_load_lds(
      (const __attribute__((address_space(1))) unsigned int*)g,
      (__attribute__((address_space(3))) unsigned int*)l, 16, 0, 0);
}

// ---------------- fp32 -> bf16 conversion (vectorized x4) ------------------
__global__ __launch_bounds__(256) void cvt_kernel(const float* __restrict__ in,
                                                  unsigned short* __restrict__ out,
                                                  int n4) {
  int i = blockIdx.x * 256 + threadIdx.x;
  if (i >= n4) return;
  float4 v = reinterpret_cast<const float4*>(in)[i];
  ushort4 o;
  o.x = f2bf(v.x); o.y = f2bf(v.y); o.z = f2bf(v.z); o.w = f2bf(v.w);
  reinterpret_cast<ushort4*>(out)[i] = o;
}

// ---------------- NT GEMM: C[M][N] = A[M][K] * W[N][K]^T  (bf16 MFMA) ------
// 128x128 tile, BK=64, 4 waves (2x2), 4x4 16x16x32 frags/wave (m97 structure)
// MODE 0: bf16 row-major out; MODE 1: f32 row-major out;
// MODE 2: bf16 scatter to Vt[b][kv][d][s] (row=token=(b,s), col=(kv,d))
template <int MODE>
__global__ __launch_bounds__(256) void gemm_bt(const unsigned short* __restrict__ A,
                                               const unsigned short* __restrict__ Bw,
                                               void* __restrict__ Cout, int N, int K) {
  __shared__ __align__(16) unsigned short As[128 * 64];
  __shared__ __align__(16) unsigned short Bs[128 * 64];
  const int tid = threadIdx.x;
  const int w = tid >> 6, l = tid & 63;
  const int ntiles = N >> 7;
  const int bm = (blockIdx.x / ntiles) << 7;
  const int bn = (blockIdx.x % ntiles) << 7;
  const int wm = (w >> 1) << 6;
  const int wn = (w & 1) << 6;

  f32x4 zero4 = {0.f, 0.f, 0.f, 0.f};
  f32x4 acc[4][4];
#pragma unroll
  for (int i = 0; i < 4; i++)
#pragma unroll
    for (int j = 0; j < 4; j++) acc[i][j] = zero4;

  const int srow = w * 8 + (l >> 3);  // row within 32-row staging chunk
  const int scol = (l & 7) * 16;      // byte col within 128B row
  const unsigned short* Ag = A + (size_t)(bm + srow) * K;
  const unsigned short* Bg = Bw + (size_t)(bn + srow) * K;

  for (int kt = 0; kt < K; kt += 64) {
#pragma unroll
    for (int it = 0; it < 4; it++)
      gload_lds16((const char*)(Ag + (size_t)(it * 32) * K + kt) + scol,
                  As + (it * 32 + w * 8) * 64);
#pragma unroll
    for (int it = 0; it < 4; it++)
      gload_lds16((const char*)(Bg + (size_t)(it * 32) * K + kt) + scol,
                  Bs + (it * 32 + w * 8) * 64);
    __syncthreads();
#pragma unroll
    for (int kk = 0; kk < 2; kk++) {
      bf16x8 af[4], bfv[4];
#pragma unroll
      for (int i = 0; i < 4; i++)
        af[i] = *reinterpret_cast<const bf16x8*>(As + (wm + i * 16 + (l & 15)) * 64 +
                                                 kk * 32 + ((l >> 4) << 3));
#pragma unroll
      for (int j = 0; j < 4; j++)
        bfv[j] = *reinterpret_cast<const bf16x8*>(Bs + (wn + j * 16 + (l & 15)) * 64 +
                                                  kk * 32 + ((l >> 4) << 3));
#pragma unroll
      for (int i = 0; i < 4; i++)
#pragma unroll
        for (int j = 0; j < 4; j++)
          acc[i][j] = __builtin_amdgcn_mfma_f32_16x16x32_bf16(af[i], bfv[j], acc[i][j], 0, 0, 0);
    }
    __syncthreads();
  }

  // epilogue: D row = (l>>4)*4 + r, col = l&15 (m89-verified layout)
#pragma unroll
  for (int i = 0; i < 4; i++) {
#pragma unroll
    for (int j = 0; j < 4; j++) {
#pragma unroll
      for (int r = 0; r < 4; r++) {
        const int row = bm + wm + i * 16 + ((l >> 4) << 2) + r;
        const int col = bn + wn + j * 16 + (l & 15);
        const float v = acc[i][j][r];
        if (MODE == 0) {
          ((unsigned short*)Cout)[(size_t)row * N + col] = f2bf(v);
        } else if (MODE == 1) {
          ((float*)Cout)[(size_t)row * N + col] = v;
        } else {
          const int b_ = row >> 11, s_ = row & 2047;
          const int kvh = col >> 7, d = col & 127;
          ((unsigned short*)Cout)[((size_t)((b_ * NKVc + kvh) * HDc + d) << 11) + s_] = f2bf(v);
        }
      }
    }
  }
}

// ---------------- RoPE + relayout: raw[token][h*128+d] -> dst[b][h][s][d] --
template <int NHEADS, bool SCALE>
__global__ __launch_bounds__(256) void rope_kernel(const unsigned short* __restrict__ raw,
                                                   unsigned short* __restrict__ dst) {
  const int t = blockIdx.x * 256 + threadIdx.x;
  const int d = t & 63;
  const int h = (t >> 6) & (NHEADS - 1);
  const int tok = t / (64 * NHEADS);
  const int b = tok >> 11, s = tok & 2047;
  const float inv = exp2f(-0.2076205059304601f * (float)d);  // 10000^(-d/64)
  const float ang = (float)s * inv;
  float sn, c;
  sincosf(ang, &sn, &c);
  const size_t src = (size_t)tok * (NHEADS * 128) + h * 128 + d;
  const float x0 = bf2f(raw[src]);
  const float x1 = bf2f(raw[src + 64]);
  float o0 = x0 * c - x1 * sn;
  float o1 = x1 * c + x0 * sn;
  if (SCALE) { o0 *= SM_SCALE; o1 *= SM_SCALE; }
  const size_t db = ((size_t)(b * NHEADS + h) * Sc + s) * HDc + d;
  dst[db] = f2bf(o0);
  dst[db + 64] = f2bf(o1);
}

// ---------------- causal GQA flash attention (R2) ---------------------------
// 512 blocks = 32 bh x 16 pairs; pair p handles q-tiles (31-p, p): exactly 33
// KV-tile iterations per block -> perfect balance. Double-buffered K/V with
// counted vmcnt(8) prefetch across barriers (prefetch spans the pair boundary).
__global__ __launch_bounds__(256) void attn_kernel(const unsigned short* __restrict__ Q,
                                                   const unsigned short* __restrict__ Kr,
                                                   const unsigned short* __restrict__ Vt,
                                                   unsigned short* __restrict__ O) {
  __shared__ __align__(16) unsigned short Ks[2][64 * 128];  // [kv][d] swizzled
  __shared__ __align__(16) unsigned short Vs[2][128 * 64];  // [d][kv] swizzled
  __shared__ __align__(16) unsigned short Ps[4][16 * 64];   // per-wave P, swizzled

  const int tid = threadIdx.x, w = tid >> 6, l = tid & 63;
  const int p = blockIdx.x & 15, bh = blockIdx.x >> 4;
  const int b = bh >> 4, h = bh & 15, kvh = h >> 2;

  const int qt0 = 31 - p, qt1 = p;
  const int nIter = 33;  // (qt0+1) + (qt1+1)

  const unsigned short* Kb = Kr + (size_t)(b * NKVc + kvh) * Sc * HDc;
  const unsigned short* Vb = Vt + (size_t)(b * NKVc + kvh) * HDc * Sc;

  // staging addressing: K 16 rows/issue (256B rows), V 32 rows/issue (128B rows)
  const int krow = w * 4 + (l >> 4);
  const int kcb = ((l & 15) * 16) ^ ((krow & 7) << 4);  // pre-swizzled source col
  const int vrow = w * 8 + (l >> 3);
  const int vcb = ((l & 7) * 16) ^ ((vrow & 7) << 4);

  auto stage = [&](int buf, int kt) {
#pragma unroll
    for (int it = 0; it < 4; it++)
      gload_lds16((const char*)(Kb + (size_t)(kt * 64 + it * 16 + krow) * HDc) + kcb,
                  &Ks[buf][(it * 16 + w * 4) * 128]);
#pragma unroll
    for (int it = 0; it < 4; it++)
      gload_lds16((const char*)(Vb + (size_t)(it * 32 + vrow) * Sc + kt * 64) + vcb,
                  &Vs[buf][(it * 32 + w * 8) * 64]);
  };

  bf16x8 qf[4];
  auto loadQ = [&](int qt) {
    const unsigned short* Qb =
        Q + ((size_t)bh * Sc + (qt << 6) + w * 16 + (l & 15)) * HDc + ((l >> 4) << 3);
#pragma unroll
    for (int kk = 0; kk < 4; kk++)
      qf[kk] = *reinterpret_cast<const bf16x8*>(Qb + kk * 32);
  };

  f32x4 zero4 = {0.f, 0.f, 0.f, 0.f};
  f32x4 oacc[8];
#pragma unroll
  for (int i = 0; i < 8; i++) oacc[i] = zero4;
  float mrow[4] = {-1e30f, -1e30f, -1e30f, -1e30f};
  float sume[4] = {0.f, 0.f, 0.f, 0.f};

  loadQ(qt0);
  stage(0, 0);

  int qt = qt0, phase = 0, kt = 0, buf = 0;
  for (int i = 0; i < nIter; ++i) {
    if (i + 1 < nIter) {
      const int nkt = (kt == qt) ? 0 : kt + 1;
      stage(buf ^ 1, nkt);
      asm volatile("s_waitcnt vmcnt(8)" ::: "memory");  // cur buf landed; 8 in flight
    } else {
      asm volatile("s_waitcnt vmcnt(0)" ::: "memory");
    }
    __builtin_amdgcn_s_barrier();

    const unsigned short* Kcur = Ks[buf];
    const unsigned short* Vcur = Vs[buf];

    // S = Q K^T : 4 kv-16 frags x 4 k-chunks
    f32x4 sacc[4];
#pragma unroll
    for (int nf = 0; nf < 4; nf++) sacc[nf] = zero4;
#pragma unroll
    for (int nf = 0; nf < 4; nf++) {
      const int kr = nf * 16 + (l & 15);
#pragma unroll
      for (int kk = 0; kk < 4; kk++) {
        const int cb = (kk * 32 + ((l >> 4) << 3)) * 2;
        bf16x8 kf = *reinterpret_cast<const bf16x8*>((const char*)Kcur + kr * 256 +
                                                     (cb ^ ((kr & 7) << 4)));
        sacc[nf] = __builtin_amdgcn_mfma_f32_16x16x32_bf16(qf[kk], kf, sacc[nf], 0, 0, 0);
      }
    }

    if (kt == qt) {  // causal mask on diagonal tile
      const int qg = (w << 4) + ((l >> 4) << 2);
#pragma unroll
      for (int nf = 0; nf < 4; nf++) {
        const int kvl = nf * 16 + (l & 15);
#pragma unroll
        for (int r = 0; r < 4; r++)
          if (kvl > qg + r) sacc[nf][r] = -1e30f;
      }
    }

    // online softmax (row stats per (group,reg); 16-lane shfl reduce)
    float alpha[4];
#pragma unroll
    for (int r = 0; r < 4; r++) {
      float t = fmaxf(fmaxf(sacc[0][r], sacc[1][r]), fmaxf(sacc[2][r], sacc[3][r]));
#pragma unroll
      for (int m = 1; m < 16; m <<= 1) t = fmaxf(t, __shfl_xor(t, m));
      const float mn = fmaxf(mrow[r], t);
      alpha[r] = exp2f((mrow[r] - mn) * LOG2E);
      mrow[r] = mn;
      sume[r] *= alpha[r];
    }
#pragma unroll
    for (int i2 = 0; i2 < 8; i2++) {
      f32x4 t = oacc[i2];
      t[0] *= alpha[0]; t[1] *= alpha[1]; t[2] *= alpha[2]; t[3] *= alpha[3];
      oacc[i2] = t;
    }

    unsigned short* Pw = Ps[w];
#pragma unroll
    for (int nf = 0; nf < 4; nf++) {
#pragma unroll
      for (int r = 0; r < 4; r++) {
        const float pv = exp2f((sacc[nf][r] - mrow[r]) * LOG2E);
        sume[r] += pv;
        const int prow = ((l >> 4) << 2) + r;
        const int pbyte = (prow * 128 + (nf * 16 + (l & 15)) * 2) ^ ((prow & 7) << 4);
        *(unsigned short*)((char*)Pw + pbyte) = f2bf(pv);
      }
    }

    // O += P V  (A = P from LDS swizzled, B = V^T rows contiguous swizzled)
#pragma unroll
    for (int kk = 0; kk < 2; kk++) {
      const int prow = l & 15;
      const int pbyte = (prow * 128 + (kk * 32 + ((l >> 4) << 3)) * 2) ^ ((prow & 7) << 4);
      bf16x8 pf = *reinterpret_cast<const bf16x8*>((const char*)Pw + pbyte);
#pragma unroll
      for (int df = 0; df < 8; df++) {
        const int vr = df * 16 + (l & 15);
        const int cb = (kk * 32 + ((l >> 4) << 3)) * 2;
        bf16x8 vf = *reinterpret_cast<const bf16x8*>((const char*)Vcur + vr * 128 +
                                                     (cb ^ ((vr & 7) << 4)));
        oacc[df] = __builtin_amdgcn_mfma_f32_16x16x32_bf16(pf, vf, oacc[df], 0, 0, 0);
      }
    }

    asm volatile("s_waitcnt lgkmcnt(0)" ::: "memory");  // all LDS reads done
    __builtin_amdgcn_s_barrier();                       // before next overwrite

    if (kt == qt) {
      // finalize this q-tile: reduce denominators, write O
      float rinv[4];
#pragma unroll
      for (int r = 0; r < 4; r++) {
        float t = sume[r];
#pragma unroll
        for (int m = 1; m < 16; m <<= 1) t += __shfl_xor(t, m);
        rinv[r] = 1.0f / t;
      }
      unsigned short* Ob = O +
          ((size_t)(b * Sc + (qt << 6) + (w << 4) + ((l >> 4) << 2)) * (NHc * HDc)) +
          h * HDc + (l & 15);
#pragma unroll
      for (int df = 0; df < 8; df++)
#pragma unroll
        for (int r = 0; r < 4; r++)
          Ob[(size_t)r * (NHc * HDc) + df * 16] = f2bf(oacc[df][r] * rinv[r]);

      if (phase == 0) {
        phase = 1; qt = qt1; kt = 0;
#pragma unroll
        for (int i2 = 0; i2 < 8; i2++) oacc[i2] = zero4;
#pragma unroll
        for (int r = 0; r < 4; r++) { mrow[r] = -1e30f; sume[r] = 0.f; }
        loadQ(qt1);
      }
    } else {
      kt++;
    }
    buf ^= 1;
  }
}

// ---------------------------------------------------------------------------
extern "C" void kernel_launch(void* const* d_in, const int* in_sizes, int n_in,
                              void* d_out, int out_size, void* d_ws, size_t ws_size,
                              hipStream_t stream) {
  (void)in_sizes; (void)n_in; (void)out_size; (void)ws_size;
  const float* X = (const float*)d_in[0];
  const float* Wq = (const float*)d_in[1];
  const float* Wk = (const float*)d_in[2];
  const float* Wv = (const float*)d_in[3];
  const float* Wo = (const float*)d_in[4];

  char* ws = (char*)d_ws;
  unsigned short* Xbf = (unsigned short*)(ws + 0);          // 4096x2048
  unsigned short* Wqb = (unsigned short*)(ws + 16777216);   // 2048x2048
  unsigned short* Wkb = (unsigned short*)(ws + 25165824);   // 512x2048
  unsigned short* Wvb = (unsigned short*)(ws + 27262976);   // 512x2048
  unsigned short* Wob = (unsigned short*)(ws + 29360128);   // 2048x2048
  unsigned short* Qraw = (unsigned short*)(ws + 37748736);  // 4096x2048
  unsigned short* Kraw = (unsigned short*)(ws + 54525952);  // 4096x512
  unsigned short* Vt = (unsigned short*)(ws + 58720256);    // [b][kv][d][s]
  unsigned short* Qr = (unsigned short*)(ws + 62914560);    // [b][h][s][d]
  unsigned short* Kr = (unsigned short*)(ws + 79691776);    // [b][kv][s][d]
  unsigned short* Ows = (unsigned short*)(ws + 83886080);   // 4096x2048

  cvt_kernel<<<8192, 256, 0, stream>>>(X, Xbf, 2097152);
  cvt_kernel<<<4096, 256, 0, stream>>>(Wq, Wqb, 1048576);
  cvt_kernel<<<1024, 256, 0, stream>>>(Wk, Wkb, 262144);
  cvt_kernel<<<1024, 256, 0, stream>>>(Wv, Wvb, 262144);
  cvt_kernel<<<4096, 256, 0, stream>>>(Wo, Wob, 1048576);

  gemm_bt<0><<<32 * 16, 256, 0, stream>>>(Xbf, Wqb, Qraw, 2048, 2048);
  gemm_bt<0><<<32 * 4, 256, 0, stream>>>(Xbf, Wkb, Kraw, 512, 2048);
  gemm_bt<2><<<32 * 4, 256, 0, stream>>>(Xbf, Wvb, Vt, 512, 2048);

  rope_kernel<16, true><<<16384, 256, 0, stream>>>(Qraw, Qr);
  rope_kernel<4, false><<<4096, 256, 0, stream>>>(Kraw, Kr);

  attn_kernel<<<512, 256, 0, stream>>>(Qr, Kr, Vt, Ows);

  gemm_bt<1><<<32 * 16, 256, 0, stream>>>(Ows, Wob, d_out, 2048, 2048);
}

// Round 3
// 285.786 us; speedup vs baseline: 1.3558x; 1.1009x over previous
//
#include <hip/hip_runtime.h>
#include <cstdint>
#include <cstddef>
#include <type_traits>

// ---------------------------------------------------------------------------
// FlashSparseAttention: X->QKV proj -> RoPE -> causal GQA flash attn -> O proj
// B=2 S=2048 H=2048 NH=16 NKV=4 HD=128, fp32 in/out, bf16 MFMA internally.
// R3: attn 8-wave, immediate-offset LDS addressing (precomputed swizzle bases),
//     defer-max, native bf16 cvt, LOG2E folded into Q prescale; fused QKV GEMM.
// ---------------------------------------------------------------------------

typedef __bf16 bf16x8 __attribute__((ext_vector_type(8)));
typedef float f32x4 __attribute__((ext_vector_type(4)));

#define DEVFN static __device__ __forceinline__

constexpr int Bc = 2, Sc = 2048, Hc = 2048, NHc = 16, NKVc = 4, HDc = 128;
constexpr float SM_SCALE = 0.08838834764831845f;   // 1/sqrt(128)
constexpr float LOG2E = 1.4426950408889634f;
constexpr float QSCALE = 0.127517431f;             // SM_SCALE * LOG2E
constexpr float DEFER_THR = 11.0f;                 // ~8 nats in log2 domain

DEVFN unsigned short f2bf(float f) {
  __bf16 h = (__bf16)f;                            // native v_cvt RNE
  return __builtin_bit_cast(unsigned short, h);
}
DEVFN float bf2f(unsigned short s) { return __uint_as_float(((unsigned)s) << 16); }

DEVFN void gload_lds16(const void* g, void* l) {
  __builtin_amdgcn_global_load_lds(
      (const __attribute__((address_space(1))) unsigned int*)g,
      (__attribute__((address_space(3))) unsigned int*)l, 16, 0, 0);
}

// ---------------- fp32 -> bf16 conversion (vectorized x4) ------------------
__global__ __launch_bounds__(256) void cvt_kernel(const float* __restrict__ in,
                                                  unsigned short* __restrict__ out,
                                                  int n4) {
  int i = blockIdx.x * 256 + threadIdx.x;
  if (i >= n4) return;
  float4 v = reinterpret_cast<const float4*>(in)[i];
  ushort4 o;
  o.x = f2bf(v.x); o.y = f2bf(v.y); o.z = f2bf(v.z); o.w = f2bf(v.w);
  reinterpret_cast<ushort4*>(out)[i] = o;
}

// ---------------- fused QKV NT GEMM: [4096 x 3072] = X * [Wq;Wk;Wv]^T ------
// 128x128 tile, BK=64, 4 waves, m97 structure. Epilogue routes per-block:
// cols [0,2048) -> Qraw, [2048,2560) -> Kraw, [2560,3072) -> Vt scatter.
__global__ __launch_bounds__(256) void gemm_qkv(const unsigned short* __restrict__ A,
                                                const unsigned short* __restrict__ Bw,
                                                unsigned short* __restrict__ Qraw,
                                                unsigned short* __restrict__ Kraw,
                                                unsigned short* __restrict__ Vt) {
  constexpr int N = 3072, K = 2048;
  __shared__ __align__(16) unsigned short As[128 * 64];
  __shared__ __align__(16) unsigned short Bs[128 * 64];
  const int tid = threadIdx.x;
  const int w = tid >> 6, l = tid & 63;
  const int bm = (blockIdx.x / 24) << 7;
  const int bn = (blockIdx.x % 24) << 7;
  const int wm = (w >> 1) << 6;
  const int wn = (w & 1) << 6;

  f32x4 zero4 = {0.f, 0.f, 0.f, 0.f};
  f32x4 acc[4][4];
#pragma unroll
  for (int i = 0; i < 4; i++)
#pragma unroll
    for (int j = 0; j < 4; j++) acc[i][j] = zero4;

  const int srow = w * 8 + (l >> 3);
  const int scol = (l & 7) * 16;
  const unsigned short* Ag = A + (size_t)(bm + srow) * K;
  const unsigned short* Bg = Bw + (size_t)(bn + srow) * K;

  for (int kt = 0; kt < K; kt += 64) {
#pragma unroll
    for (int it = 0; it < 4; it++)
      gload_lds16((const char*)(Ag + (size_t)(it * 32) * K + kt) + scol,
                  As + (it * 32 + w * 8) * 64);
#pragma unroll
    for (int it = 0; it < 4; it++)
      gload_lds16((const char*)(Bg + (size_t)(it * 32) * K + kt) + scol,
                  Bs + (it * 32 + w * 8) * 64);
    __syncthreads();
#pragma unroll
    for (int kk = 0; kk < 2; kk++) {
      bf16x8 af[4], bfv[4];
#pragma unroll
      for (int i = 0; i < 4; i++)
        af[i] = *reinterpret_cast<const bf16x8*>(As + (wm + i * 16 + (l & 15)) * 64 +
                                                 kk * 32 + ((l >> 4) << 3));
#pragma unroll
      for (int j = 0; j < 4; j++)
        bfv[j] = *reinterpret_cast<const bf16x8*>(Bs + (wn + j * 16 + (l & 15)) * 64 +
                                                  kk * 32 + ((l >> 4) << 3));
#pragma unroll
      for (int i = 0; i < 4; i++)
#pragma unroll
        for (int j = 0; j < 4; j++)
          acc[i][j] = __builtin_amdgcn_mfma_f32_16x16x32_bf16(af[i], bfv[j], acc[i][j], 0, 0, 0);
    }
    __syncthreads();
  }

#pragma unroll
  for (int i = 0; i < 4; i++) {
#pragma unroll
    for (int j = 0; j < 4; j++) {
#pragma unroll
      for (int r = 0; r < 4; r++) {
        const int row = bm + wm + i * 16 + ((l >> 4) << 2) + r;
        const int col = bn + wn + j * 16 + (l & 15);
        const unsigned short v = f2bf(acc[i][j][r]);
        if (bn < 2048) {
          Qraw[(size_t)row * 2048 + col] = v;
        } else if (bn < 2560) {
          Kraw[(size_t)row * 512 + (col - 2048)] = v;
        } else {
          const int cv = col - 2560;
          const int b_ = row >> 11, s_ = row & 2047;
          const int kvh = cv >> 7, d = cv & 127;
          Vt[((size_t)((b_ * NKVc + kvh) * HDc + d) << 11) + s_] = v;
        }
      }
    }
  }
}

// ---------------- NT GEMM (f32 out) for O projection -----------------------
__global__ __launch_bounds__(256) void gemm_o(const unsigned short* __restrict__ A,
                                              const unsigned short* __restrict__ Bw,
                                              float* __restrict__ Cout) {
  constexpr int N = 2048, K = 2048;
  __shared__ __align__(16) unsigned short As[128 * 64];
  __shared__ __align__(16) unsigned short Bs[128 * 64];
  const int tid = threadIdx.x;
  const int w = tid >> 6, l = tid & 63;
  const int bm = (blockIdx.x / 16) << 7;
  const int bn = (blockIdx.x % 16) << 7;
  const int wm = (w >> 1) << 6;
  const int wn = (w & 1) << 6;

  f32x4 zero4 = {0.f, 0.f, 0.f, 0.f};
  f32x4 acc[4][4];
#pragma unroll
  for (int i = 0; i < 4; i++)
#pragma unroll
    for (int j = 0; j < 4; j++) acc[i][j] = zero4;

  const int srow = w * 8 + (l >> 3);
  const int scol = (l & 7) * 16;
  const unsigned short* Ag = A + (size_t)(bm + srow) * K;
  const unsigned short* Bg = Bw + (size_t)(bn + srow) * K;

  for (int kt = 0; kt < K; kt += 64) {
#pragma unroll
    for (int it = 0; it < 4; it++)
      gload_lds16((const char*)(Ag + (size_t)(it * 32) * K + kt) + scol,
                  As + (it * 32 + w * 8) * 64);
#pragma unroll
    for (int it = 0; it < 4; it++)
      gload_lds16((const char*)(Bg + (size_t)(it * 32) * K + kt) + scol,
                  Bs + (it * 32 + w * 8) * 64);
    __syncthreads();
#pragma unroll
    for (int kk = 0; kk < 2; kk++) {
      bf16x8 af[4], bfv[4];
#pragma unroll
      for (int i = 0; i < 4; i++)
        af[i] = *reinterpret_cast<const bf16x8*>(As + (wm + i * 16 + (l & 15)) * 64 +
                                                 kk * 32 + ((l >> 4) << 3));
#pragma unroll
      for (int j = 0; j < 4; j++)
        bfv[j] = *reinterpret_cast<const bf16x8*>(Bs + (wn + j * 16 + (l & 15)) * 64 +
                                                  kk * 32 + ((l >> 4) << 3));
#pragma unroll
      for (int i = 0; i < 4; i++)
#pragma unroll
        for (int j = 0; j < 4; j++)
          acc[i][j] = __builtin_amdgcn_mfma_f32_16x16x32_bf16(af[i], bfv[j], acc[i][j], 0, 0, 0);
    }
    __syncthreads();
  }

#pragma unroll
  for (int i = 0; i < 4; i++)
#pragma unroll
    for (int j = 0; j < 4; j++)
#pragma unroll
      for (int r = 0; r < 4; r++) {
        const int row = bm + wm + i * 16 + ((l >> 4) << 2) + r;
        const int col = bn + wn + j * 16 + (l & 15);
        Cout[(size_t)row * N + col] = acc[i][j][r];
      }
}

// ---------------- RoPE + relayout: raw[token][h*128+d] -> dst[b][h][s][d] --
template <int NHEADS, bool SCALE>
__global__ __launch_bounds__(256) void rope_kernel(const unsigned short* __restrict__ raw,
                                                   unsigned short* __restrict__ dst) {
  const int t = blockIdx.x * 256 + threadIdx.x;
  const int d = t & 63;
  const int h = (t >> 6) & (NHEADS - 1);
  const int tok = t / (64 * NHEADS);
  const int b = tok >> 11, s = tok & 2047;
  const float inv = exp2f(-0.2076205059304601f * (float)d);  // 10000^(-d/64)
  const float ang = (float)s * inv;
  float sn, c;
  sincosf(ang, &sn, &c);
  const size_t src = (size_t)tok * (NHEADS * 128) + h * 128 + d;
  const float x0 = bf2f(raw[src]);
  const float x1 = bf2f(raw[src + 64]);
  float o0 = x0 * c - x1 * sn;
  float o1 = x1 * c + x0 * sn;
  if (SCALE) { o0 *= QSCALE; o1 *= QSCALE; }   // 1/sqrt(HD) * log2(e) folded
  const size_t db = ((size_t)(b * NHEADS + h) * Sc + s) * HDc + d;
  dst[db] = f2bf(o0);
  dst[db + 64] = f2bf(o1);
}

// ---------------- causal GQA flash attention (R3) ---------------------------
// 256 blocks = 32 bh x 8 pairs; 8 waves; Q-tile 128 rows (16/wave); KV tile 64.
// Pair p handles q-tiles (15-p, p) -> exactly 34 KV iterations per block.
// LDS map: K dbuf @0/@16384, V dbuf @32768/@49152, P per-wave @65536+w*2048.
// All swizzled LDS read/write addresses = precomputed lane base + imm offset.
__global__ __launch_bounds__(512, 4) void attn_kernel(const unsigned short* __restrict__ Q,
                                                      const unsigned short* __restrict__ Kr,
                                                      const unsigned short* __restrict__ Vt,
                                                      unsigned short* __restrict__ O) {
  __shared__ __align__(16) char smem[81920];

  const int tid = threadIdx.x, w = tid >> 6, l = tid & 63;
  const int g = l >> 4, lc = l & 15;
  const int p = blockIdx.x & 7, bh = blockIdx.x >> 3;
  const int b = bh >> 4, h = bh & 15, kvh = h >> 2;
  const int qt1 = p;

  const char* Kb = (const char*)(Kr + (size_t)(b * NKVc + kvh) * Sc * HDc);
  const char* Vb = (const char*)(Vt + (size_t)(b * NKVc + kvh) * HDc * Sc);

  // staging constants (512 threads): K 32 rows/issue (256B), V 64 rows/issue (128B)
  const int ksr = tid >> 4;
  const int kcb = ((tid & 15) * 16) ^ ((ksr & 7) << 4);
  const int vsr = tid >> 3;
  const int vcb = ((tid & 7) * 16) ^ ((vsr & 7) << 4);
  char* kdst = smem + w * 1024;
  char* vdst = smem + 32768 + w * 1024;

  auto stage = [&](int bufoff, int kt_) {
    gload_lds16(Kb + (size_t)(kt_ * 64 + ksr) * 256 + kcb, kdst + bufoff);
    gload_lds16(Kb + (size_t)(kt_ * 64 + 32 + ksr) * 256 + kcb, kdst + bufoff + 8192);
    gload_lds16(Vb + (size_t)vsr * 4096 + kt_ * 128 + vcb, vdst + bufoff);
    gload_lds16(Vb + (size_t)(64 + vsr) * 4096 + kt_ * 128 + vcb, vdst + bufoff + 8192);
  };

  // precomputed swizzled read bases (byte offsets into smem)
  const int swb = ((g ^ lc) & 3) * 16 + ((lc >> 2) & 1) * 64;
  const int kbA = lc * 256 + swb;            // K: + BUF + nf*4096 + (kk>>1)*128 (^64 if kk odd)
  const int vbA = lc * 128 + swb;            // V: +32768+BUF + df*2048 (^64 if k2 odd); P read: +pwb
  const int pwb = 65536 + w * 2048;
  // P write bases: 8 combos (r, nf1); imm = 32*((nf&1)^((r>>1)&1))
  int pwo[8];
#pragma unroll
  for (int r = 0; r < 4; r++)
#pragma unroll
    for (int n1 = 0; n1 < 2; n1++)
      pwo[r * 2 + n1] = pwb + (g * 4 + r) * 128 + (lc & 7) * 2 +
                        16 * (((lc >> 3) & 1) ^ (r & 1)) + 64 * (n1 ^ (g & 1));

  bf16x8 qf[4];
  auto loadQ = [&](int qtl) {
    const unsigned short* Qb =
        Q + ((size_t)bh * Sc + qtl * 128 + w * 16 + lc) * HDc + (g << 3);
#pragma unroll
    for (int kk = 0; kk < 4; kk++)
      qf[kk] = *reinterpret_cast<const bf16x8*>(Qb + kk * 32);
  };

  f32x4 zero4 = {0.f, 0.f, 0.f, 0.f};
  f32x4 oacc[8];
#pragma unroll
  for (int i = 0; i < 8; i++) oacc[i] = zero4;
  float mreg[4] = {-1e30f, -1e30f, -1e30f, -1e30f};
  float sume[4] = {0.f, 0.f, 0.f, 0.f};

  int qt = 15 - p, kt = 0, phase = 0, it = 0;
  loadQ(qt);
  stage(0, 0);

  auto iter = [&](auto bufc) {
    constexpr int BUF = decltype(bufc)::value;
    if (it < 33) {
      stage(BUF ^ 16384, (kt == 2 * qt + 1) ? 0 : kt + 1);
      asm volatile("s_waitcnt vmcnt(4)" ::: "memory");
    } else {
      asm volatile("s_waitcnt vmcnt(0)" ::: "memory");
    }
    __builtin_amdgcn_s_barrier();

    // S = Q K^T (scaled by 1/sqrt(d)*log2e via Q prescale)
    f32x4 sacc[4];
#pragma unroll
    for (int nf = 0; nf < 4; nf++) sacc[nf] = zero4;
#pragma unroll
    for (int nf = 0; nf < 4; nf++) {
#pragma unroll
      for (int kk = 0; kk < 4; kk++) {
        const bf16x8 kf = *reinterpret_cast<const bf16x8*>(
            smem + BUF + ((kk & 1) ? (kbA ^ 64) : kbA) + nf * 4096 + (kk >> 1) * 128);
        sacc[nf] = __builtin_amdgcn_mfma_f32_16x16x32_bf16(qf[kk], kf, sacc[nf], 0, 0, 0);
      }
    }

    if (kt >= 2 * qt) {  // diagonal tiles: causal mask
      const int qrow = (w << 4) + (g << 2) - ((kt - 2 * qt) << 6);
#pragma unroll
      for (int nf = 0; nf < 4; nf++) {
        const int kvl = nf * 16 + lc;
#pragma unroll
        for (int r = 0; r < 4; r++)
          if (kvl > qrow + r) sacc[nf][r] = -1e30f;
      }
    }

    // online softmax with defer-max
    float tmax[4];
#pragma unroll
    for (int r = 0; r < 4; r++) {
      float t = fmaxf(fmaxf(sacc[0][r], sacc[1][r]), fmaxf(sacc[2][r], sacc[3][r]));
#pragma unroll
      for (int m = 1; m < 16; m <<= 1) t = fmaxf(t, __shfl_xor(t, m));
      tmax[r] = t;
    }
    const bool ok = (tmax[0] <= mreg[0] + DEFER_THR) && (tmax[1] <= mreg[1] + DEFER_THR) &&
                    (tmax[2] <= mreg[2] + DEFER_THR) && (tmax[3] <= mreg[3] + DEFER_THR);
    if (!__all(ok)) {
      float alpha[4];
#pragma unroll
      for (int r = 0; r < 4; r++) {
        const float mn = fmaxf(mreg[r], tmax[r]);
        alpha[r] = exp2f(mreg[r] - mn);
        mreg[r] = mn;
        sume[r] *= alpha[r];
      }
#pragma unroll
      for (int i2 = 0; i2 < 8; i2++) {
        f32x4 t = oacc[i2];
        t[0] *= alpha[0]; t[1] *= alpha[1]; t[2] *= alpha[2]; t[3] *= alpha[3];
        oacc[i2] = t;
      }
    }

    // P = exp2(S - m), write bf16 to per-wave LDS (imm-offset swizzled)
#pragma unroll
    for (int nf = 0; nf < 4; nf++) {
#pragma unroll
      for (int r = 0; r < 4; r++) {
        const float pv = exp2f(sacc[nf][r] - mreg[r]);
        sume[r] += pv;
        *(unsigned short*)(smem + pwo[r * 2 + (nf >> 1)] +
                           32 * ((nf & 1) ^ ((r >> 1) & 1))) = f2bf(pv);
      }
    }

    // O += P V
#pragma unroll
    for (int k2 = 0; k2 < 2; k2++) {
      const int sb = k2 ? (vbA ^ 64) : vbA;
      const bf16x8 pf = *reinterpret_cast<const bf16x8*>(smem + pwb + sb);
#pragma unroll
      for (int df = 0; df < 8; df++) {
        const bf16x8 vf =
            *reinterpret_cast<const bf16x8*>(smem + 32768 + BUF + sb + df * 2048);
        oacc[df] = __builtin_amdgcn_mfma_f32_16x16x32_bf16(pf, vf, oacc[df], 0, 0, 0);
      }
    }

    asm volatile("s_waitcnt lgkmcnt(0)" ::: "memory");
    __builtin_amdgcn_s_barrier();

    if (kt == 2 * qt + 1) {  // q-tile finished
      float rinv[4];
#pragma unroll
      for (int r = 0; r < 4; r++) {
        float t = sume[r];
#pragma unroll
        for (int m = 1; m < 16; m <<= 1) t += __shfl_xor(t, m);
        rinv[r] = 1.0f / t;
      }
      unsigned short* Ob = O +
          ((size_t)(b * Sc + qt * 128 + (w << 4) + (g << 2)) * (NHc * HDc)) +
          h * HDc + lc;
#pragma unroll
      for (int df = 0; df < 8; df++)
#pragma unroll
        for (int r = 0; r < 4; r++)
          Ob[(size_t)r * (NHc * HDc) + df * 16] = f2bf(oacc[df][r] * rinv[r]);

      if (phase == 0) {
        phase = 1; qt = qt1; kt = 0;
#pragma unroll
        for (int i2 = 0; i2 < 8; i2++) oacc[i2] = zero4;
#pragma unroll
        for (int r = 0; r < 4; r++) { mreg[r] = -1e30f; sume[r] = 0.f; }
        loadQ(qt1);
      }
    } else {
      kt++;
    }
    it++;
  };

  for (int ii = 0; ii < 17; ++ii) {
    iter(std::integral_constant<int, 0>{});
    iter(std::integral_constant<int, 16384>{});
  }
}

// ---------------------------------------------------------------------------
extern "C" void kernel_launch(void* const* d_in, const int* in_sizes, int n_in,
                              void* d_out, int out_size, void* d_ws, size_t ws_size,
                              hipStream_t stream) {
  (void)in_sizes; (void)n_in; (void)out_size; (void)ws_size;
  const float* X = (const float*)d_in[0];
  const float* Wq = (const float*)d_in[1];
  const float* Wk = (const float*)d_in[2];
  const float* Wv = (const float*)d_in[3];
  const float* Wo = (const float*)d_in[4];

  char* ws = (char*)d_ws;
  unsigned short* Xbf  = (unsigned short*)(ws + 0);         // 4096x2048 (16MB)
  unsigned short* Wqkv = (unsigned short*)(ws + 16777216);  // 3072x2048 (12.6MB)
  unsigned short* Wob  = (unsigned short*)(ws + 29360128);  // 2048x2048 (8MB)
  unsigned short* Qraw = (unsigned short*)(ws + 37748736);  // 4096x2048 (16MB)
  unsigned short* Kraw = (unsigned short*)(ws + 54525952);  // 4096x512  (4MB)
  unsigned short* Vt   = (unsigned short*)(ws + 58720256);  // [b][kv][d][s] (4MB)
  unsigned short* Qr   = (unsigned short*)(ws + 62914560);  // [b][h][s][d] (16MB)
  unsigned short* Kr   = (unsigned short*)(ws + 79691776);  // [b][kv][s][d] (4MB)
  unsigned short* Ows  = (unsigned short*)(ws + 83886080);  // 4096x2048 (16MB)

  cvt_kernel<<<8192, 256, 0, stream>>>(X, Xbf, 2097152);
  cvt_kernel<<<4096, 256, 0, stream>>>(Wq, Wqkv, 1048576);
  cvt_kernel<<<1024, 256, 0, stream>>>(Wk, Wqkv + 4194304, 262144);
  cvt_kernel<<<1024, 256, 0, stream>>>(Wv, Wqkv + 5242880, 262144);
  cvt_kernel<<<4096, 256, 0, stream>>>(Wo, Wob, 1048576);

  gemm_qkv<<<32 * 24, 256, 0, stream>>>(Xbf, Wqkv, Qraw, Kraw, Vt);

  rope_kernel<16, true><<<16384, 256, 0, stream>>>(Qraw, Qr);
  rope_kernel<4, false><<<4096, 256, 0, stream>>>(Kraw, Kr);

  attn_kernel<<<256, 512, 0, stream>>>(Qr, Kr, Vt, Ows);

  gemm_o<<<32 * 16, 256, 0, stream>>>(Ows, Wob, (float*)d_out);
}

// Round 4
// 271.564 us; speedup vs baseline: 1.4268x; 1.0524x over previous
//
#include <hip/hip_runtime.h>
#include <cstdint>
#include <cstddef>
#include <type_traits>

// ---------------------------------------------------------------------------
// FlashSparseAttention: X->QKV proj -> RoPE -> causal GQA flash attn -> O proj
// B=2 S=2048 H=2048 NH=16 NKV=4 HD=128, fp32 in/out, bf16 MFMA internally.
// R4: GEMMs rewritten as 3-slot-ring deep-pipelined MFMA kernels (BK=32,
//     counted vmcnt, 1 barrier/K-tile, swizzled LDS, setprio, XCD swizzle).
//     Q-RoPE fused into attention's Q load (rope<16> kernel eliminated).
// ---------------------------------------------------------------------------

typedef __bf16 bf16x8 __attribute__((ext_vector_type(8)));
typedef float f32x4 __attribute__((ext_vector_type(4)));

#define DEVFN static __device__ __forceinline__

constexpr int Bc = 2, Sc = 2048, Hc = 2048, NHc = 16, NKVc = 4, HDc = 128;
constexpr float SM_SCALE = 0.08838834764831845f;   // 1/sqrt(128)
constexpr float LOG2E = 1.4426950408889634f;
constexpr float QSCALE = 0.127517431f;             // SM_SCALE * LOG2E
constexpr float DEFER_THR = 11.0f;                 // ~8 nats in log2 domain

DEVFN unsigned short f2bf(float f) {
  __bf16 h = (__bf16)f;                            // native v_cvt RNE
  return __builtin_bit_cast(unsigned short, h);
}
DEVFN float bf2f(unsigned short s) { return __uint_as_float(((unsigned)s) << 16); }

DEVFN void gload_lds16(const void* g, void* l) {
  __builtin_amdgcn_global_load_lds(
      (const __attribute__((address_space(1))) unsigned int*)g,
      (__attribute__((address_space(3))) unsigned int*)l, 16, 0, 0);
}

// ---------------- fp32 -> bf16 conversion (vectorized x4) ------------------
__global__ __launch_bounds__(256) void cvt_kernel(const float* __restrict__ in,
                                                  unsigned short* __restrict__ out,
                                                  int n4) {
  int i = blockIdx.x * 256 + threadIdx.x;
  if (i >= n4) return;
  float4 v = reinterpret_cast<const float4*>(in)[i];
  ushort4 o;
  o.x = f2bf(v.x); o.y = f2bf(v.y); o.z = f2bf(v.z); o.w = f2bf(v.w);
  reinterpret_cast<ushort4*>(out)[i] = o;
}

// ---------------- ring-pipelined NT GEMM (bf16 MFMA, K=2048) ----------------
// Tile: BM = MREP*32 rows x 256 cols, BK=32, 8 waves (2M x 4N), 512 threads.
// LDS: 3 ring slots; slot = A(BM x 32) + B(256 x 32) bf16, rows packed 2/128B
// with 16B-chunk XOR swizzle (CH ^= lrow&7). Staging = global_load_lds with
// pre-swizzled global source (linear LDS dest). Per K-tile: counted
// vmcnt(NCH), one s_barrier, stage tile j+2, 12 ds_read_b128, 32/16 MFMA.
// MODE 1: f32 out (N=2048, grid 256 = 32x8); MODE 2: fused QKV epilogue
// (N=3072, grid 192 = 16x12; Q bf16 / K bf16 / V transposed scatter).
template <int MREP, int MODE>
__global__ __launch_bounds__(512, 2) void gemm_ring(const unsigned short* __restrict__ A,
                                                    const unsigned short* __restrict__ Bw,
                                                    void* __restrict__ o0,
                                                    void* __restrict__ o1,
                                                    void* __restrict__ o2) {
  constexpr int ACH = MREP / 4;          // A 8KB-chunks per K-tile
  constexpr int NCH = ACH + 2;           // total chunks (loads/thread) per tile
  constexpr int ABY = ACH * 8192;        // A bytes per slot
  constexpr int SLOT = ABY + 16384;      // + B bytes
  constexpr int T = 64;                  // K/32
  __shared__ __align__(16) char smem[3 * SLOT];

  const int tid = threadIdx.x;
  const int w = tid >> 6, l = tid & 63;
  const int g = l >> 4, lc = l & 15;
  const int wm = w >> 2, wn = w & 3;

  // XCD-aware block swizzle (grid % 8 == 0 in both modes)
  const int bid = blockIdx.x;
  int bm, bn;
  if (MODE == 2) {
    const int wgid = (bid & 7) * 24 + (bid >> 3);
    bm = (wgid & 15) << 8;               // 16 row tiles of 256
    bn = (wgid >> 4) << 8;               // 12 col tiles of 256
  } else {
    const int wgid = (bid & 7) * 32 + (bid >> 3);
    bm = (wgid & 31) << 7;               // 32 row tiles of 128
    bn = (wgid >> 5) << 8;               // 8 col tiles of 256
  }

  // ---- staging lane constants (pre-swizzled global source) ----
  const int u = (tid & 7) ^ ((tid >> 3) & 7);
  const int sr = ((tid >> 3) << 1) + (u >> 2);   // row within 128-row chunk
  const int scb = (u & 3) << 4;                  // col byte (pre-swizzled)
  const char* Agp = (const char*)A + ((size_t)(bm + sr) << 12) + scb;  // K=2048 -> 4KB rows
  const char* Bgp = (const char*)Bw + ((size_t)(bn + sr) << 12) + scb;
  char* ldst = smem + tid * 16;

  auto stage = [&](int slot, int kt) {
    const int kb = kt * 64;
#pragma unroll
    for (int c = 0; c < ACH; c++)
      gload_lds16(Agp + ((size_t)c << 19) + kb, ldst + slot + c * 8192);
#pragma unroll
    for (int c = 0; c < 2; c++)
      gload_lds16(Bgp + ((size_t)c << 19) + kb, ldst + slot + ABY + c * 8192);
  };

  // ---- read lane constants (swizzled, frag index -> +1024B immediate) ----
  const int CH = (((lc & 1) << 2) + g) ^ (lc >> 1);
  const int laneA = (wm * (MREP * 8) + (lc >> 1)) * 128 + CH * 16;
  const int laneB = ABY + (wn * 32 + (lc >> 1)) * 128 + CH * 16;

  f32x4 zero4 = {0.f, 0.f, 0.f, 0.f};
  f32x4 acc[MREP][4];
#pragma unroll
  for (int i = 0; i < MREP; i++)
#pragma unroll
    for (int j = 0; j < 4; j++) acc[i][j] = zero4;

  int r0 = 0, r1 = SLOT, r2 = 2 * SLOT;
  stage(r0, 0);
  stage(r1, 1);

  for (int j = 0; j < T; ++j) {
    if (j < T - 1) {
      asm volatile("s_waitcnt vmcnt(%0)" ::"n"(NCH) : "memory");
    } else {
      asm volatile("s_waitcnt vmcnt(0)" ::: "memory");
    }
    asm volatile("s_barrier" ::: "memory");
    if (j + 2 < T) stage(r2, j + 2);

    const char* pa = smem + r0 + laneA;
    const char* pb = smem + r0 + laneB;
    bf16x8 af[MREP], bfr[4];
#pragma unroll
    for (int mi = 0; mi < MREP; mi++) af[mi] = *(const bf16x8*)(pa + mi * 1024);
#pragma unroll
    for (int nj = 0; nj < 4; nj++) bfr[nj] = *(const bf16x8*)(pb + nj * 1024);

    __builtin_amdgcn_s_setprio(1);
#pragma unroll
    for (int mi = 0; mi < MREP; mi++)
#pragma unroll
      for (int nj = 0; nj < 4; nj++)
        acc[mi][nj] = __builtin_amdgcn_mfma_f32_16x16x32_bf16(af[mi], bfr[nj], acc[mi][nj], 0, 0, 0);
    __builtin_amdgcn_s_setprio(0);

    const int t = r0; r0 = r1; r1 = r2; r2 = t;
  }

  // ---- epilogue ----
#pragma unroll
  for (int mi = 0; mi < MREP; mi++) {
#pragma unroll
    for (int nj = 0; nj < 4; nj++) {
#pragma unroll
      for (int r = 0; r < 4; r++) {
        const int row = bm + wm * (MREP * 16) + mi * 16 + (g << 2) + r;
        const int col = bn + wn * 64 + nj * 16 + lc;
        const float v = acc[mi][nj][r];
        if (MODE == 1) {
          ((float*)o0)[(size_t)row * 2048 + col] = v;
        } else {
          const unsigned short q = f2bf(v);
          if (bn < 2048) {
            ((unsigned short*)o0)[(size_t)row * 2048 + col] = q;
          } else if (bn < 2560) {
            ((unsigned short*)o1)[(size_t)row * 512 + (col - 2048)] = q;
          } else {
            const int cv = col - 2560;
            ((unsigned short*)o2)[((size_t)(((row >> 11) * NKVc + (cv >> 7)) * HDc + (cv & 127)) << 11) +
                                  (row & 2047)] = q;
          }
        }
      }
    }
  }
}

// ---------------- RoPE + relayout (K only): raw[tok][kv*128+d] -> [b][kv][s][d]
template <int NHEADS, bool SCALE>
__global__ __launch_bounds__(256) void rope_kernel(const unsigned short* __restrict__ raw,
                                                   unsigned short* __restrict__ dst) {
  const int t = blockIdx.x * 256 + threadIdx.x;
  const int d = t & 63;
  const int h = (t >> 6) & (NHEADS - 1);
  const int tok = t / (64 * NHEADS);
  const int b = tok >> 11, s = tok & 2047;
  const float inv = exp2f(-0.2076205059304601f * (float)d);  // 10000^(-d/64)
  const float ang = (float)s * inv;
  float sn, c;
  sincosf(ang, &sn, &c);
  const size_t src = (size_t)tok * (NHEADS * 128) + h * 128 + d;
  const float x0 = bf2f(raw[src]);
  const float x1 = bf2f(raw[src + 64]);
  float o0 = x0 * c - x1 * sn;
  float o1 = x1 * c + x0 * sn;
  if (SCALE) { o0 *= QSCALE; o1 *= QSCALE; }
  const size_t db = ((size_t)(b * NHEADS + h) * Sc + s) * HDc + d;
  dst[db] = f2bf(o0);
  dst[db + 64] = f2bf(o1);
}

// ---------------- causal GQA flash attention (R3 structure + fused Q-RoPE) --
__global__ __launch_bounds__(512, 4) void attn_kernel(const unsigned short* __restrict__ Qraw,
                                                      const unsigned short* __restrict__ Kr,
                                                      const unsigned short* __restrict__ Vt,
                                                      unsigned short* __restrict__ O) {
  __shared__ __align__(16) char smem[81920];

  const int tid = threadIdx.x, w = tid >> 6, l = tid & 63;
  const int g = l >> 4, lc = l & 15;
  const int p = blockIdx.x & 7, bh = blockIdx.x >> 3;
  const int b = bh >> 4, h = bh & 15, kvh = h >> 2;
  const int qt1 = p;

  const char* Kb = (const char*)(Kr + (size_t)(b * NKVc + kvh) * Sc * HDc);
  const char* Vb = (const char*)(Vt + (size_t)(b * NKVc + kvh) * HDc * Sc);

  const int ksr = tid >> 4;
  const int kcb = ((tid & 15) * 16) ^ ((ksr & 7) << 4);
  const int vsr = tid >> 3;
  const int vcb = ((tid & 7) * 16) ^ ((vsr & 7) << 4);
  char* kdst = smem + w * 1024;
  char* vdst = smem + 32768 + w * 1024;

  auto stage = [&](int bufoff, int kt_) {
    gload_lds16(Kb + (size_t)(kt_ * 64 + ksr) * 256 + kcb, kdst + bufoff);
    gload_lds16(Kb + (size_t)(kt_ * 64 + 32 + ksr) * 256 + kcb, kdst + bufoff + 8192);
    gload_lds16(Vb + (size_t)vsr * 4096 + kt_ * 128 + vcb, vdst + bufoff);
    gload_lds16(Vb + (size_t)(64 + vsr) * 4096 + kt_ * 128 + vcb, vdst + bufoff + 8192);
  };

  const int swb = ((g ^ lc) & 3) * 16 + ((lc >> 2) & 1) * 64;
  const int kbA = lc * 256 + swb;
  const int vbA = lc * 128 + swb;
  const int pwb = 65536 + w * 2048;
  int pwo[8];
#pragma unroll
  for (int r = 0; r < 4; r++)
#pragma unroll
    for (int n1 = 0; n1 < 2; n1++)
      pwo[r * 2 + n1] = pwb + (g * 4 + r) * 128 + (lc & 7) * 2 +
                        16 * (((lc >> 3) & 1) ^ (r & 1)) + 64 * (n1 ^ (g & 1));

  bf16x8 qf[4];
  // Q load + fused RoPE + 1/sqrt(d)*log2e scale. Source: Qraw[tok][h*128+d].
  auto loadQ = [&](int qtl) {
    const int srow = qtl * 128 + w * 16 + lc;   // position s within sequence
    const unsigned short* Qb = Qraw + ((size_t)(b * Sc + srow) << 11) + h * 128 + (g << 3);
    float x[4][8];
#pragma unroll
    for (int kk = 0; kk < 4; kk++) {
      const bf16x8 v = *reinterpret_cast<const bf16x8*>(Qb + kk * 32);
#pragma unroll
      for (int j = 0; j < 8; j++) x[kk][j] = (float)v[j];
    }
#pragma unroll
    for (int kk = 0; kk < 2; kk++) {
#pragma unroll
      for (int j = 0; j < 8; j++) {
        const int d = kk * 32 + (g << 3) + j;
        const float ang = (float)srow * exp2f(-0.2076205059304601f * (float)d);
        float sn, cs;
        sincosf(ang, &sn, &cs);
        qf[kk][j] = (__bf16)((x[kk][j] * cs - x[kk + 2][j] * sn) * QSCALE);
        qf[kk + 2][j] = (__bf16)((x[kk + 2][j] * cs + x[kk][j] * sn) * QSCALE);
      }
    }
  };

  f32x4 zero4 = {0.f, 0.f, 0.f, 0.f};
  f32x4 oacc[8];
#pragma unroll
  for (int i = 0; i < 8; i++) oacc[i] = zero4;
  float mreg[4] = {-1e30f, -1e30f, -1e30f, -1e30f};
  float sume[4] = {0.f, 0.f, 0.f, 0.f};

  int qt = 15 - p, kt = 0, phase = 0, it = 0;
  loadQ(qt);
  stage(0, 0);

  auto iter = [&](auto bufc) {
    constexpr int BUF = decltype(bufc)::value;
    if (it < 33) {
      stage(BUF ^ 16384, (kt == 2 * qt + 1) ? 0 : kt + 1);
      asm volatile("s_waitcnt vmcnt(4)" ::: "memory");
    } else {
      asm volatile("s_waitcnt vmcnt(0)" ::: "memory");
    }
    __builtin_amdgcn_s_barrier();

    f32x4 sacc[4];
#pragma unroll
    for (int nf = 0; nf < 4; nf++) sacc[nf] = zero4;
#pragma unroll
    for (int nf = 0; nf < 4; nf++) {
#pragma unroll
      for (int kk = 0; kk < 4; kk++) {
        const bf16x8 kf = *reinterpret_cast<const bf16x8*>(
            smem + BUF + ((kk & 1) ? (kbA ^ 64) : kbA) + nf * 4096 + (kk >> 1) * 128);
        sacc[nf] = __builtin_amdgcn_mfma_f32_16x16x32_bf16(qf[kk], kf, sacc[nf], 0, 0, 0);
      }
    }

    if (kt >= 2 * qt) {
      const int qrow = (w << 4) + (g << 2) - ((kt - 2 * qt) << 6);
#pragma unroll
      for (int nf = 0; nf < 4; nf++) {
        const int kvl = nf * 16 + lc;
#pragma unroll
        for (int r = 0; r < 4; r++)
          if (kvl > qrow + r) sacc[nf][r] = -1e30f;
      }
    }

    float tmax[4];
#pragma unroll
    for (int r = 0; r < 4; r++) {
      float t = fmaxf(fmaxf(sacc[0][r], sacc[1][r]), fmaxf(sacc[2][r], sacc[3][r]));
#pragma unroll
      for (int m = 1; m < 16; m <<= 1) t = fmaxf(t, __shfl_xor(t, m));
      tmax[r] = t;
    }
    const bool ok = (tmax[0] <= mreg[0] + DEFER_THR) && (tmax[1] <= mreg[1] + DEFER_THR) &&
                    (tmax[2] <= mreg[2] + DEFER_THR) && (tmax[3] <= mreg[3] + DEFER_THR);
    if (!__all(ok)) {
      float alpha[4];
#pragma unroll
      for (int r = 0; r < 4; r++) {
        const float mn = fmaxf(mreg[r], tmax[r]);
        alpha[r] = exp2f(mreg[r] - mn);
        mreg[r] = mn;
        sume[r] *= alpha[r];
      }
#pragma unroll
      for (int i2 = 0; i2 < 8; i2++) {
        f32x4 t = oacc[i2];
        t[0] *= alpha[0]; t[1] *= alpha[1]; t[2] *= alpha[2]; t[3] *= alpha[3];
        oacc[i2] = t;
      }
    }

#pragma unroll
    for (int nf = 0; nf < 4; nf++) {
#pragma unroll
      for (int r = 0; r < 4; r++) {
        const float pv = exp2f(sacc[nf][r] - mreg[r]);
        sume[r] += pv;
        *(unsigned short*)(smem + pwo[r * 2 + (nf >> 1)] +
                           32 * ((nf & 1) ^ ((r >> 1) & 1))) = f2bf(pv);
      }
    }

#pragma unroll
    for (int k2 = 0; k2 < 2; k2++) {
      const int sb = k2 ? (vbA ^ 64) : vbA;
      const bf16x8 pf = *reinterpret_cast<const bf16x8*>(smem + pwb + sb);
#pragma unroll
      for (int df = 0; df < 8; df++) {
        const bf16x8 vf =
            *reinterpret_cast<const bf16x8*>(smem + 32768 + BUF + sb + df * 2048);
        oacc[df] = __builtin_amdgcn_mfma_f32_16x16x32_bf16(pf, vf, oacc[df], 0, 0, 0);
      }
    }

    asm volatile("s_waitcnt lgkmcnt(0)" ::: "memory");
    __builtin_amdgcn_s_barrier();

    if (kt == 2 * qt + 1) {
      float rinv[4];
#pragma unroll
      for (int r = 0; r < 4; r++) {
        float t = sume[r];
#pragma unroll
        for (int m = 1; m < 16; m <<= 1) t += __shfl_xor(t, m);
        rinv[r] = 1.0f / t;
      }
      unsigned short* Ob = O +
          ((size_t)(b * Sc + qt * 128 + (w << 4) + (g << 2)) * (NHc * HDc)) +
          h * HDc + lc;
#pragma unroll
      for (int df = 0; df < 8; df++)
#pragma unroll
        for (int r = 0; r < 4; r++)
          Ob[(size_t)r * (NHc * HDc) + df * 16] = f2bf(oacc[df][r] * rinv[r]);

      if (phase == 0) {
        phase = 1; qt = qt1; kt = 0;
#pragma unroll
        for (int i2 = 0; i2 < 8; i2++) oacc[i2] = zero4;
#pragma unroll
        for (int r = 0; r < 4; r++) { mreg[r] = -1e30f; sume[r] = 0.f; }
        loadQ(qt1);
      }
    } else {
      kt++;
    }
    it++;
  };

  for (int ii = 0; ii < 17; ++ii) {
    iter(std::integral_constant<int, 0>{});
    iter(std::integral_constant<int, 16384>{});
  }
}

// ---------------------------------------------------------------------------
extern "C" void kernel_launch(void* const* d_in, const int* in_sizes, int n_in,
                              void* d_out, int out_size, void* d_ws, size_t ws_size,
                              hipStream_t stream) {
  (void)in_sizes; (void)n_in; (void)out_size; (void)ws_size;
  const float* X = (const float*)d_in[0];
  const float* Wq = (const float*)d_in[1];
  const float* Wk = (const float*)d_in[2];
  const float* Wv = (const float*)d_in[3];
  const float* Wo = (const float*)d_in[4];

  char* ws = (char*)d_ws;
  unsigned short* Xbf  = (unsigned short*)(ws + 0);         // 4096x2048 (16MB)
  unsigned short* Wqkv = (unsigned short*)(ws + 16777216);  // 3072x2048 (12.6MB)
  unsigned short* Wob  = (unsigned short*)(ws + 29360128);  // 2048x2048 (8MB)
  unsigned short* Qraw = (unsigned short*)(ws + 37748736);  // 4096x2048 (16MB)
  unsigned short* Kraw = (unsigned short*)(ws + 54525952);  // 4096x512  (4MB)
  unsigned short* Vt   = (unsigned short*)(ws + 58720256);  // [b][kv][d][s] (4MB)
  unsigned short* Kr   = (unsigned short*)(ws + 79691776);  // [b][kv][s][d] (4MB)
  unsigned short* Ows  = (unsigned short*)(ws + 83886080);  // 4096x2048 (16MB)

  cvt_kernel<<<8192, 256, 0, stream>>>(X, Xbf, 2097152);
  cvt_kernel<<<4096, 256, 0, stream>>>(Wq, Wqkv, 1048576);
  cvt_kernel<<<1024, 256, 0, stream>>>(Wk, Wqkv + 4194304, 262144);
  cvt_kernel<<<1024, 256, 0, stream>>>(Wv, Wqkv + 5242880, 262144);
  cvt_kernel<<<4096, 256, 0, stream>>>(Wo, Wob, 1048576);

  gemm_ring<8, 2><<<192, 512, 0, stream>>>(Xbf, Wqkv, Qraw, Kraw, Vt);

  rope_kernel<4, false><<<4096, 256, 0, stream>>>(Kraw, Kr);

  attn_kernel<<<256, 512, 0, stream>>>(Qraw, Kr, Vt, Ows);

  gemm_ring<4, 1><<<256, 512, 0, stream>>>(Ows, Wob, d_out, nullptr, nullptr);
}

// Round 5
// 249.565 us; speedup vs baseline: 1.5526x; 1.0881x over previous
//
#include <hip/hip_runtime.h>
#include <cstdint>
#include <cstddef>
#include <type_traits>

// ---------------------------------------------------------------------------
// FlashSparseAttention: X->QKV proj -> RoPE -> causal GQA flash attn -> O proj
// B=2 S=2048 H=2048 NH=16 NKV=4 HD=128, fp32 in/out, bf16 MFMA internally.
// R5: RoPE via precomputed cos/sin table (no sincosf in hot kernels — R4's
//     fused-trig loadQ caused spills + Payne-Hanek calls, 64->145us).
//     Weight converts fused into one kernel.
// ---------------------------------------------------------------------------

typedef __bf16 bf16x8 __attribute__((ext_vector_type(8)));
typedef float f32x4 __attribute__((ext_vector_type(4)));

#define DEVFN static __device__ __forceinline__

constexpr int Bc = 2, Sc = 2048, Hc = 2048, NHc = 16, NKVc = 4, HDc = 128;
constexpr float SM_SCALE = 0.08838834764831845f;   // 1/sqrt(128)
constexpr float QSCALE = 0.127517431f;             // SM_SCALE * log2(e)
constexpr float DEFER_THR = 11.0f;                 // ~8 nats in log2 domain

DEVFN unsigned short f2bf(float f) {
  __bf16 h = (__bf16)f;                            // native v_cvt RNE
  return __builtin_bit_cast(unsigned short, h);
}
DEVFN float bf2f(unsigned short s) { return __uint_as_float(((unsigned)s) << 16); }

DEVFN void gload_lds16(const void* g, void* l) {
  __builtin_amdgcn_global_load_lds(
      (const __attribute__((address_space(1))) unsigned int*)g,
      (__attribute__((address_space(3))) unsigned int*)l, 16, 0, 0);
}

// ---------------- fp32 -> bf16 conversion (vectorized x4) ------------------
__global__ __launch_bounds__(256) void cvt_kernel(const float* __restrict__ in,
                                                  unsigned short* __restrict__ out,
                                                  int n4) {
  int i = blockIdx.x * 256 + threadIdx.x;
  if (i >= n4) return;
  float4 v = reinterpret_cast<const float4*>(in)[i];
  ushort4 o;
  o.x = f2bf(v.x); o.y = f2bf(v.y); o.z = f2bf(v.z); o.w = f2bf(v.w);
  reinterpret_cast<ushort4*>(out)[i] = o;
}

// ---------------- fused weight conversion (Wq|Wk|Wv -> Wqkv, Wo -> Wob) ----
__global__ __launch_bounds__(256) void cvt_weights(const float* __restrict__ Wq,
                                                   const float* __restrict__ Wk,
                                                   const float* __restrict__ Wv,
                                                   const float* __restrict__ Wo,
                                                   unsigned short* __restrict__ Wqkv,
                                                   unsigned short* __restrict__ Wob) {
  const int i = blockIdx.x * 256 + threadIdx.x;  // float4 index, total 2621440
  const float* src;
  unsigned short* dst;
  int off;
  if (i < 1048576) { src = Wq; dst = Wqkv; off = i; }
  else if (i < 1310720) { src = Wk; dst = Wqkv + 4194304; off = i - 1048576; }
  else if (i < 1572864) { src = Wv; dst = Wqkv + 5242880; off = i - 1310720; }
  else { src = Wo; dst = Wob; off = i - 1572864; }
  float4 v = reinterpret_cast<const float4*>(src)[off];
  ushort4 o;
  o.x = f2bf(v.x); o.y = f2bf(v.y); o.z = f2bf(v.z); o.w = f2bf(v.w);
  reinterpret_cast<ushort4*>(dst)[off] = o;
}

// ---------------- RoPE cos/sin table: [s][d] d in 0..63, f32 ---------------
__global__ __launch_bounds__(256) void rope_table(float* __restrict__ cosT,
                                                  float* __restrict__ sinT) {
  const int i = blockIdx.x * 256 + threadIdx.x;  // 131072 = 2048*64
  const int s = i >> 6, d = i & 63;
  const float inv = exp2f(-0.2076205059304601f * (float)d);  // 10000^(-d/64)
  float sn, c;
  sincosf((float)s * inv, &sn, &c);
  cosT[i] = c;
  sinT[i] = sn;
}

// ---------------- ring-pipelined NT GEMM (bf16 MFMA, K=2048) ----------------
// Tile: BM = MREP*32 rows x 256 cols, BK=32, 8 waves (2M x 4N), 512 threads.
// 3-slot LDS ring, counted vmcnt, 1 barrier/K-tile, swizzled LDS reads,
// pre-swizzled global staging source, setprio around MFMA, XCD block swizzle.
template <int MREP, int MODE>
__global__ __launch_bounds__(512, 2) void gemm_ring(const unsigned short* __restrict__ A,
                                                    const unsigned short* __restrict__ Bw,
                                                    void* __restrict__ o0,
                                                    void* __restrict__ o1,
                                                    void* __restrict__ o2) {
  constexpr int ACH = MREP / 4;
  constexpr int NCH = ACH + 2;
  constexpr int ABY = ACH * 8192;
  constexpr int SLOT = ABY + 16384;
  constexpr int T = 64;
  __shared__ __align__(16) char smem[3 * SLOT];

  const int tid = threadIdx.x;
  const int w = tid >> 6, l = tid & 63;
  const int g = l >> 4, lc = l & 15;
  const int wm = w >> 2, wn = w & 3;

  const int bid = blockIdx.x;
  int bm, bn;
  if (MODE == 2) {
    const int wgid = (bid & 7) * 24 + (bid >> 3);
    bm = (wgid & 15) << 8;
    bn = (wgid >> 4) << 8;
  } else {
    const int wgid = (bid & 7) * 32 + (bid >> 3);
    bm = (wgid & 31) << 7;
    bn = (wgid >> 5) << 8;
  }

  const int u = (tid & 7) ^ ((tid >> 3) & 7);
  const int sr = ((tid >> 3) << 1) + (u >> 2);
  const int scb = (u & 3) << 4;
  const char* Agp = (const char*)A + ((size_t)(bm + sr) << 12) + scb;
  const char* Bgp = (const char*)Bw + ((size_t)(bn + sr) << 12) + scb;
  char* ldst = smem + tid * 16;

  auto stage = [&](int slot, int kt) {
    const int kb = kt * 64;
#pragma unroll
    for (int c = 0; c < ACH; c++)
      gload_lds16(Agp + ((size_t)c << 19) + kb, ldst + slot + c * 8192);
#pragma unroll
    for (int c = 0; c < 2; c++)
      gload_lds16(Bgp + ((size_t)c << 19) + kb, ldst + slot + ABY + c * 8192);
  };

  const int CH = (((lc & 1) << 2) + g) ^ (lc >> 1);
  const int laneA = (wm * (MREP * 8) + (lc >> 1)) * 128 + CH * 16;
  const int laneB = ABY + (wn * 32 + (lc >> 1)) * 128 + CH * 16;

  f32x4 zero4 = {0.f, 0.f, 0.f, 0.f};
  f32x4 acc[MREP][4];
#pragma unroll
  for (int i = 0; i < MREP; i++)
#pragma unroll
    for (int j = 0; j < 4; j++) acc[i][j] = zero4;

  int r0 = 0, r1 = SLOT, r2 = 2 * SLOT;
  stage(r0, 0);
  stage(r1, 1);

  for (int j = 0; j < T; ++j) {
    if (j < T - 1) {
      asm volatile("s_waitcnt vmcnt(%0)" ::"n"(NCH) : "memory");
    } else {
      asm volatile("s_waitcnt vmcnt(0)" ::: "memory");
    }
    asm volatile("s_barrier" ::: "memory");
    if (j + 2 < T) stage(r2, j + 2);

    const char* pa = smem + r0 + laneA;
    const char* pb = smem + r0 + laneB;
    bf16x8 af[MREP], bfr[4];
#pragma unroll
    for (int mi = 0; mi < MREP; mi++) af[mi] = *(const bf16x8*)(pa + mi * 1024);
#pragma unroll
    for (int nj = 0; nj < 4; nj++) bfr[nj] = *(const bf16x8*)(pb + nj * 1024);

    __builtin_amdgcn_s_setprio(1);
#pragma unroll
    for (int mi = 0; mi < MREP; mi++)
#pragma unroll
      for (int nj = 0; nj < 4; nj++)
        acc[mi][nj] = __builtin_amdgcn_mfma_f32_16x16x32_bf16(af[mi], bfr[nj], acc[mi][nj], 0, 0, 0);
    __builtin_amdgcn_s_setprio(0);

    const int t = r0; r0 = r1; r1 = r2; r2 = t;
  }

#pragma unroll
  for (int mi = 0; mi < MREP; mi++) {
#pragma unroll
    for (int nj = 0; nj < 4; nj++) {
#pragma unroll
      for (int r = 0; r < 4; r++) {
        const int row = bm + wm * (MREP * 16) + mi * 16 + (g << 2) + r;
        const int col = bn + wn * 64 + nj * 16 + lc;
        const float v = acc[mi][nj][r];
        if (MODE == 1) {
          ((float*)o0)[(size_t)row * 2048 + col] = v;
        } else {
          const unsigned short q = f2bf(v);
          if (bn < 2048) {
            ((unsigned short*)o0)[(size_t)row * 2048 + col] = q;
          } else if (bn < 2560) {
            ((unsigned short*)o1)[(size_t)row * 512 + (col - 2048)] = q;
          } else {
            const int cv = col - 2560;
            ((unsigned short*)o2)[((size_t)(((row >> 11) * NKVc + (cv >> 7)) * HDc + (cv & 127)) << 11) +
                                  (row & 2047)] = q;
          }
        }
      }
    }
  }
}

// ---------------- K RoPE + relayout: raw[tok][kv*128+d] -> [b][kv][s][d] ----
__global__ __launch_bounds__(256) void rope_k(const unsigned short* __restrict__ raw,
                                              unsigned short* __restrict__ dst,
                                              const float* __restrict__ cosT,
                                              const float* __restrict__ sinT) {
  const int t = blockIdx.x * 256 + threadIdx.x;
  const int d = t & 63;
  const int h = (t >> 6) & 3;
  const int tok = t >> 8;
  const int b = tok >> 11, s = tok & 2047;
  const float c = cosT[(s << 6) + d];
  const float sn = sinT[(s << 6) + d];
  const size_t src = (size_t)tok * 512 + h * 128 + d;
  const float x0 = bf2f(raw[src]);
  const float x1 = bf2f(raw[src + 64]);
  const size_t db = ((size_t)(b * NKVc + h) * Sc + s) * HDc + d;
  dst[db] = f2bf(x0 * c - x1 * sn);
  dst[db + 64] = f2bf(x1 * c + x0 * sn);
}

// ---------------- causal GQA flash attention (table-based fused Q-RoPE) -----
__global__ __launch_bounds__(512, 4) void attn_kernel(const unsigned short* __restrict__ Qraw,
                                                      const unsigned short* __restrict__ Kr,
                                                      const unsigned short* __restrict__ Vt,
                                                      unsigned short* __restrict__ O,
                                                      const float* __restrict__ cosT,
                                                      const float* __restrict__ sinT) {
  __shared__ __align__(16) char smem[81920];

  const int tid = threadIdx.x, w = tid >> 6, l = tid & 63;
  const int g = l >> 4, lc = l & 15;
  const int p = blockIdx.x & 7, bh = blockIdx.x >> 3;
  const int b = bh >> 4, h = bh & 15, kvh = h >> 2;
  const int qt1 = p;

  const char* Kb = (const char*)(Kr + (size_t)(b * NKVc + kvh) * Sc * HDc);
  const char* Vb = (const char*)(Vt + (size_t)(b * NKVc + kvh) * HDc * Sc);

  const int ksr = tid >> 4;
  const int kcb = ((tid & 15) * 16) ^ ((ksr & 7) << 4);
  const int vsr = tid >> 3;
  const int vcb = ((tid & 7) * 16) ^ ((vsr & 7) << 4);
  char* kdst = smem + w * 1024;
  char* vdst = smem + 32768 + w * 1024;

  auto stage = [&](int bufoff, int kt_) {
    gload_lds16(Kb + (size_t)(kt_ * 64 + ksr) * 256 + kcb, kdst + bufoff);
    gload_lds16(Kb + (size_t)(kt_ * 64 + 32 + ksr) * 256 + kcb, kdst + bufoff + 8192);
    gload_lds16(Vb + (size_t)vsr * 4096 + kt_ * 128 + vcb, vdst + bufoff);
    gload_lds16(Vb + (size_t)(64 + vsr) * 4096 + kt_ * 128 + vcb, vdst + bufoff + 8192);
  };

  const int swb = ((g ^ lc) & 3) * 16 + ((lc >> 2) & 1) * 64;
  const int kbA = lc * 256 + swb;
  const int vbA = lc * 128 + swb;
  const int pwb = 65536 + w * 2048;
  int pwo[8];
#pragma unroll
  for (int r = 0; r < 4; r++)
#pragma unroll
    for (int n1 = 0; n1 < 2; n1++)
      pwo[r * 2 + n1] = pwb + (g * 4 + r) * 128 + (lc & 7) * 2 +
                        16 * (((lc >> 3) & 1) ^ (r & 1)) + 64 * (n1 ^ (g & 1));

  bf16x8 qf[4];
  // Q load + table-based RoPE + QSCALE. Qraw[tok][h*128+d]; d = kk*32+g*8+j,
  // rotate pairs (kk, kk+2).
  auto loadQ = [&](int qtl) {
    const int srow = qtl * 128 + w * 16 + lc;
    const unsigned short* Qb = Qraw + ((size_t)(b * Sc + srow) << 11) + h * 128 + (g << 3);
    float x[4][8];
#pragma unroll
    for (int kk = 0; kk < 4; kk++) {
      const bf16x8 v = *reinterpret_cast<const bf16x8*>(Qb + kk * 32);
#pragma unroll
      for (int j = 0; j < 8; j++) x[kk][j] = (float)v[j] * QSCALE;
    }
#pragma unroll
    for (int kk = 0; kk < 2; kk++) {
      const float* cp = cosT + ((size_t)srow << 6) + kk * 32 + (g << 3);
      const float* sp = sinT + ((size_t)srow << 6) + kk * 32 + (g << 3);
      const float4 c0 = *(const float4*)cp, c1 = *(const float4*)(cp + 4);
      const float4 s0 = *(const float4*)sp, s1 = *(const float4*)(sp + 4);
      const float cs[8] = {c0.x, c0.y, c0.z, c0.w, c1.x, c1.y, c1.z, c1.w};
      const float ss[8] = {s0.x, s0.y, s0.z, s0.w, s1.x, s1.y, s1.z, s1.w};
#pragma unroll
      for (int j = 0; j < 8; j++) {
        qf[kk][j] = (__bf16)(x[kk][j] * cs[j] - x[kk + 2][j] * ss[j]);
        qf[kk + 2][j] = (__bf16)(x[kk + 2][j] * cs[j] + x[kk][j] * ss[j]);
      }
    }
  };

  f32x4 zero4 = {0.f, 0.f, 0.f, 0.f};
  f32x4 oacc[8];
#pragma unroll
  for (int i = 0; i < 8; i++) oacc[i] = zero4;
  float mreg[4] = {-1e30f, -1e30f, -1e30f, -1e30f};
  float sume[4] = {0.f, 0.f, 0.f, 0.f};

  int qt = 15 - p, kt = 0, phase = 0, it = 0;
  loadQ(qt);
  stage(0, 0);

  auto iter = [&](auto bufc) {
    constexpr int BUF = decltype(bufc)::value;
    if (it < 33) {
      stage(BUF ^ 16384, (kt == 2 * qt + 1) ? 0 : kt + 1);
      asm volatile("s_waitcnt vmcnt(4)" ::: "memory");
    } else {
      asm volatile("s_waitcnt vmcnt(0)" ::: "memory");
    }
    __builtin_amdgcn_s_barrier();

    f32x4 sacc[4];
#pragma unroll
    for (int nf = 0; nf < 4; nf++) sacc[nf] = zero4;
#pragma unroll
    for (int nf = 0; nf < 4; nf++) {
#pragma unroll
      for (int kk = 0; kk < 4; kk++) {
        const bf16x8 kf = *reinterpret_cast<const bf16x8*>(
            smem + BUF + ((kk & 1) ? (kbA ^ 64) : kbA) + nf * 4096 + (kk >> 1) * 128);
        sacc[nf] = __builtin_amdgcn_mfma_f32_16x16x32_bf16(qf[kk], kf, sacc[nf], 0, 0, 0);
      }
    }

    if (kt >= 2 * qt) {
      const int qrow = (w << 4) + (g << 2) - ((kt - 2 * qt) << 6);
#pragma unroll
      for (int nf = 0; nf < 4; nf++) {
        const int kvl = nf * 16 + lc;
#pragma unroll
        for (int r = 0; r < 4; r++)
          if (kvl > qrow + r) sacc[nf][r] = -1e30f;
      }
    }

    float tmax[4];
#pragma unroll
    for (int r = 0; r < 4; r++) {
      float t = fmaxf(fmaxf(sacc[0][r], sacc[1][r]), fmaxf(sacc[2][r], sacc[3][r]));
#pragma unroll
      for (int m = 1; m < 16; m <<= 1) t = fmaxf(t, __shfl_xor(t, m));
      tmax[r] = t;
    }
    const bool ok = (tmax[0] <= mreg[0] + DEFER_THR) && (tmax[1] <= mreg[1] + DEFER_THR) &&
                    (tmax[2] <= mreg[2] + DEFER_THR) && (tmax[3] <= mreg[3] + DEFER_THR);
    if (!__all(ok)) {
      float alpha[4];
#pragma unroll
      for (int r = 0; r < 4; r++) {
        const float mn = fmaxf(mreg[r], tmax[r]);
        alpha[r] = exp2f(mreg[r] - mn);
        mreg[r] = mn;
        sume[r] *= alpha[r];
      }
#pragma unroll
      for (int i2 = 0; i2 < 8; i2++) {
        f32x4 t = oacc[i2];
        t[0] *= alpha[0]; t[1] *= alpha[1]; t[2] *= alpha[2]; t[3] *= alpha[3];
        oacc[i2] = t;
      }
    }

#pragma unroll
    for (int nf = 0; nf < 4; nf++) {
#pragma unroll
      for (int r = 0; r < 4; r++) {
        const float pv = exp2f(sacc[nf][r] - mreg[r]);
        sume[r] += pv;
        *(unsigned short*)(smem + pwo[r * 2 + (nf >> 1)] +
                           32 * ((nf & 1) ^ ((r >> 1) & 1))) = f2bf(pv);
      }
    }

#pragma unroll
    for (int k2 = 0; k2 < 2; k2++) {
      const int sb = k2 ? (vbA ^ 64) : vbA;
      const bf16x8 pf = *reinterpret_cast<const bf16x8*>(smem + pwb + sb);
#pragma unroll
      for (int df = 0; df < 8; df++) {
        const bf16x8 vf =
            *reinterpret_cast<const bf16x8*>(smem + 32768 + BUF + sb + df * 2048);
        oacc[df] = __builtin_amdgcn_mfma_f32_16x16x32_bf16(pf, vf, oacc[df], 0, 0, 0);
      }
    }

    asm volatile("s_waitcnt lgkmcnt(0)" ::: "memory");
    __builtin_amdgcn_s_barrier();

    if (kt == 2 * qt + 1) {
      float rinv[4];
#pragma unroll
      for (int r = 0; r < 4; r++) {
        float t = sume[r];
#pragma unroll
        for (int m = 1; m < 16; m <<= 1) t += __shfl_xor(t, m);
        rinv[r] = 1.0f / t;
      }
      unsigned short* Ob = O +
          ((size_t)(b * Sc + qt * 128 + (w << 4) + (g << 2)) * (NHc * HDc)) +
          h * HDc + lc;
#pragma unroll
      for (int df = 0; df < 8; df++)
#pragma unroll
        for (int r = 0; r < 4; r++)
          Ob[(size_t)r * (NHc * HDc) + df * 16] = f2bf(oacc[df][r] * rinv[r]);

      if (phase == 0) {
        phase = 1; qt = qt1; kt = 0;
#pragma unroll
        for (int i2 = 0; i2 < 8; i2++) oacc[i2] = zero4;
#pragma unroll
        for (int r = 0; r < 4; r++) { mreg[r] = -1e30f; sume[r] = 0.f; }
        loadQ(qt1);
      }
    } else {
      kt++;
    }
    it++;
  };

  for (int ii = 0; ii < 17; ++ii) {
    iter(std::integral_constant<int, 0>{});
    iter(std::integral_constant<int, 16384>{});
  }
}

// ---------------------------------------------------------------------------
extern "C" void kernel_launch(void* const* d_in, const int* in_sizes, int n_in,
                              void* d_out, int out_size, void* d_ws, size_t ws_size,
                              hipStream_t stream) {
  (void)in_sizes; (void)n_in; (void)out_size; (void)ws_size;
  const float* X = (const float*)d_in[0];
  const float* Wq = (const float*)d_in[1];
  const float* Wk = (const float*)d_in[2];
  const float* Wv = (const float*)d_in[3];
  const float* Wo = (const float*)d_in[4];

  char* ws = (char*)d_ws;
  unsigned short* Xbf  = (unsigned short*)(ws + 0);         // 4096x2048 (16MB)
  unsigned short* Wqkv = (unsigned short*)(ws + 16777216);  // 3072x2048 (12.6MB)
  unsigned short* Wob  = (unsigned short*)(ws + 29360128);  // 2048x2048 (8MB)
  unsigned short* Qraw = (unsigned short*)(ws + 37748736);  // 4096x2048 (16MB)
  unsigned short* Kraw = (unsigned short*)(ws + 54525952);  // 4096x512  (4MB)
  unsigned short* Vt   = (unsigned short*)(ws + 58720256);  // [b][kv][d][s] (4MB)
  float*          cosT = (float*)(ws + 62914560);           // 2048x64 f32 (512KB)
  float*          sinT = (float*)(ws + 63438848);           // 2048x64 f32 (512KB)
  unsigned short* Kr   = (unsigned short*)(ws + 79691776);  // [b][kv][s][d] (4MB)
  unsigned short* Ows  = (unsigned short*)(ws + 83886080);  // 4096x2048 (16MB)

  rope_table<<<512, 256, 0, stream>>>(cosT, sinT);
  cvt_kernel<<<8192, 256, 0, stream>>>(X, Xbf, 2097152);
  cvt_weights<<<10240, 256, 0, stream>>>(Wq, Wk, Wv, Wo, Wqkv, Wob);

  gemm_ring<8, 2><<<192, 512, 0, stream>>>(Xbf, Wqkv, Qraw, Kraw, Vt);

  rope_k<<<4096, 256, 0, stream>>>(Kraw, Kr, cosT, sinT);

  attn_kernel<<<256, 512, 0, stream>>>(Qraw, Kr, Vt, Ows, cosT, sinT);

  gemm_ring<4, 1><<<256, 512, 0, stream>>>(Ows, Wob, d_out, nullptr, nullptr);
}

// Round 6
// 225.941 us; speedup vs baseline: 1.7149x; 1.1046x over previous
//
#include <hip/hip_runtime.h>
#include <cstdint>
#include <cstddef>
#include <type_traits>

// ---------------------------------------------------------------------------
// FlashSparseAttention: X->QKV proj -> RoPE -> causal GQA flash attn -> O proj
// B=2 S=2048 H=2048 NH=16 NKV=4 HD=128, fp32 in/out, bf16 MFMA internally.
// R6: attn converted to 3-slot LDS ring (one barrier + counted vmcnt(4) per
//     KV-tile, stage 2 tiles ahead), launch_bounds relaxed to stop the
//     64-VGPR allocation squeeze, setprio around MFMA clusters.
// ---------------------------------------------------------------------------

typedef __bf16 bf16x8 __attribute__((ext_vector_type(8)));
typedef float f32x4 __attribute__((ext_vector_type(4)));

#define DEVFN static __device__ __forceinline__

constexpr int Bc = 2, Sc = 2048, Hc = 2048, NHc = 16, NKVc = 4, HDc = 128;
constexpr float SM_SCALE = 0.08838834764831845f;   // 1/sqrt(128)
constexpr float QSCALE = 0.127517431f;             // SM_SCALE * log2(e)
constexpr float DEFER_THR = 11.0f;                 // ~8 nats in log2 domain

DEVFN unsigned short f2bf(float f) {
  __bf16 h = (__bf16)f;                            // native v_cvt RNE
  return __builtin_bit_cast(unsigned short, h);
}
DEVFN float bf2f(unsigned short s) { return __uint_as_float(((unsigned)s) << 16); }

DEVFN void gload_lds16(const void* g, void* l) {
  __builtin_amdgcn_global_load_lds(
      (const __attribute__((address_space(1))) unsigned int*)g,
      (__attribute__((address_space(3))) unsigned int*)l, 16, 0, 0);
}

// ---------------- fp32 -> bf16 conversion (vectorized x4) ------------------
__global__ __launch_bounds__(256) void cvt_kernel(const float* __restrict__ in,
                                                  unsigned short* __restrict__ out,
                                                  int n4) {
  int i = blockIdx.x * 256 + threadIdx.x;
  if (i >= n4) return;
  float4 v = reinterpret_cast<const float4*>(in)[i];
  ushort4 o;
  o.x = f2bf(v.x); o.y = f2bf(v.y); o.z = f2bf(v.z); o.w = f2bf(v.w);
  reinterpret_cast<ushort4*>(out)[i] = o;
}

// ---------------- fused weight conversion (Wq|Wk|Wv -> Wqkv, Wo -> Wob) ----
__global__ __launch_bounds__(256) void cvt_weights(const float* __restrict__ Wq,
                                                   const float* __restrict__ Wk,
                                                   const float* __restrict__ Wv,
                                                   const float* __restrict__ Wo,
                                                   unsigned short* __restrict__ Wqkv,
                                                   unsigned short* __restrict__ Wob) {
  const int i = blockIdx.x * 256 + threadIdx.x;  // float4 index, total 2621440
  const float* src;
  unsigned short* dst;
  int off;
  if (i < 1048576) { src = Wq; dst = Wqkv; off = i; }
  else if (i < 1310720) { src = Wk; dst = Wqkv + 4194304; off = i - 1048576; }
  else if (i < 1572864) { src = Wv; dst = Wqkv + 5242880; off = i - 1310720; }
  else { src = Wo; dst = Wob; off = i - 1572864; }
  float4 v = reinterpret_cast<const float4*>(src)[off];
  ushort4 o;
  o.x = f2bf(v.x); o.y = f2bf(v.y); o.z = f2bf(v.z); o.w = f2bf(v.w);
  reinterpret_cast<ushort4*>(dst)[off] = o;
}

// ---------------- RoPE cos/sin table: [s][d] d in 0..63, f32 ---------------
__global__ __launch_bounds__(256) void rope_table(float* __restrict__ cosT,
                                                  float* __restrict__ sinT) {
  const int i = blockIdx.x * 256 + threadIdx.x;  // 131072 = 2048*64
  const int s = i >> 6, d = i & 63;
  const float inv = exp2f(-0.2076205059304601f * (float)d);  // 10000^(-d/64)
  float sn, c;
  sincosf((float)s * inv, &sn, &c);
  cosT[i] = c;
  sinT[i] = sn;
}

// ---------------- ring-pipelined NT GEMM (bf16 MFMA, K=2048) ----------------
template <int MREP, int MODE>
__global__ __launch_bounds__(512, 2) void gemm_ring(const unsigned short* __restrict__ A,
                                                    const unsigned short* __restrict__ Bw,
                                                    void* __restrict__ o0,
                                                    void* __restrict__ o1,
                                                    void* __restrict__ o2) {
  constexpr int ACH = MREP / 4;
  constexpr int NCH = ACH + 2;
  constexpr int ABY = ACH * 8192;
  constexpr int SLOT = ABY + 16384;
  constexpr int T = 64;
  __shared__ __align__(16) char smem[3 * SLOT];

  const int tid = threadIdx.x;
  const int w = tid >> 6, l = tid & 63;
  const int g = l >> 4, lc = l & 15;
  const int wm = w >> 2, wn = w & 3;

  const int bid = blockIdx.x;
  int bm, bn;
  if (MODE == 2) {
    const int wgid = (bid & 7) * 24 + (bid >> 3);
    bm = (wgid & 15) << 8;
    bn = (wgid >> 4) << 8;
  } else {
    const int wgid = (bid & 7) * 32 + (bid >> 3);
    bm = (wgid & 31) << 7;
    bn = (wgid >> 5) << 8;
  }

  const int u = (tid & 7) ^ ((tid >> 3) & 7);
  const int sr = ((tid >> 3) << 1) + (u >> 2);
  const int scb = (u & 3) << 4;
  const char* Agp = (const char*)A + ((size_t)(bm + sr) << 12) + scb;
  const char* Bgp = (const char*)Bw + ((size_t)(bn + sr) << 12) + scb;
  char* ldst = smem + tid * 16;

  auto stage = [&](int slot, int kt) {
    const int kb = kt * 64;
#pragma unroll
    for (int c = 0; c < ACH; c++)
      gload_lds16(Agp + ((size_t)c << 19) + kb, ldst + slot + c * 8192);
#pragma unroll
    for (int c = 0; c < 2; c++)
      gload_lds16(Bgp + ((size_t)c << 19) + kb, ldst + slot + ABY + c * 8192);
  };

  const int CH = (((lc & 1) << 2) + g) ^ (lc >> 1);
  const int laneA = (wm * (MREP * 8) + (lc >> 1)) * 128 + CH * 16;
  const int laneB = ABY + (wn * 32 + (lc >> 1)) * 128 + CH * 16;

  f32x4 zero4 = {0.f, 0.f, 0.f, 0.f};
  f32x4 acc[MREP][4];
#pragma unroll
  for (int i = 0; i < MREP; i++)
#pragma unroll
    for (int j = 0; j < 4; j++) acc[i][j] = zero4;

  int r0 = 0, r1 = SLOT, r2 = 2 * SLOT;
  stage(r0, 0);
  stage(r1, 1);

  for (int j = 0; j < T; ++j) {
    if (j < T - 1) {
      asm volatile("s_waitcnt vmcnt(%0)" ::"n"(NCH) : "memory");
    } else {
      asm volatile("s_waitcnt vmcnt(0)" ::: "memory");
    }
    asm volatile("s_barrier" ::: "memory");
    if (j + 2 < T) stage(r2, j + 2);

    const char* pa = smem + r0 + laneA;
    const char* pb = smem + r0 + laneB;
    bf16x8 af[MREP], bfr[4];
#pragma unroll
    for (int mi = 0; mi < MREP; mi++) af[mi] = *(const bf16x8*)(pa + mi * 1024);
#pragma unroll
    for (int nj = 0; nj < 4; nj++) bfr[nj] = *(const bf16x8*)(pb + nj * 1024);

    __builtin_amdgcn_s_setprio(1);
#pragma unroll
    for (int mi = 0; mi < MREP; mi++)
#pragma unroll
      for (int nj = 0; nj < 4; nj++)
        acc[mi][nj] = __builtin_amdgcn_mfma_f32_16x16x32_bf16(af[mi], bfr[nj], acc[mi][nj], 0, 0, 0);
    __builtin_amdgcn_s_setprio(0);

    const int t = r0; r0 = r1; r1 = r2; r2 = t;
  }

#pragma unroll
  for (int mi = 0; mi < MREP; mi++) {
#pragma unroll
    for (int nj = 0; nj < 4; nj++) {
#pragma unroll
      for (int r = 0; r < 4; r++) {
        const int row = bm + wm * (MREP * 16) + mi * 16 + (g << 2) + r;
        const int col = bn + wn * 64 + nj * 16 + lc;
        const float v = acc[mi][nj][r];
        if (MODE == 1) {
          ((float*)o0)[(size_t)row * 2048 + col] = v;
        } else {
          const unsigned short q = f2bf(v);
          if (bn < 2048) {
            ((unsigned short*)o0)[(size_t)row * 2048 + col] = q;
          } else if (bn < 2560) {
            ((unsigned short*)o1)[(size_t)row * 512 + (col - 2048)] = q;
          } else {
            const int cv = col - 2560;
            ((unsigned short*)o2)[((size_t)(((row >> 11) * NKVc + (cv >> 7)) * HDc + (cv & 127)) << 11) +
                                  (row & 2047)] = q;
          }
        }
      }
    }
  }
}

// ---------------- K RoPE + relayout: raw[tok][kv*128+d] -> [b][kv][s][d] ----
__global__ __launch_bounds__(256) void rope_k(const unsigned short* __restrict__ raw,
                                              unsigned short* __restrict__ dst,
                                              const float* __restrict__ cosT,
                                              const float* __restrict__ sinT) {
  const int t = blockIdx.x * 256 + threadIdx.x;
  const int d = t & 63;
  const int h = (t >> 6) & 3;
  const int tok = t >> 8;
  const int b = tok >> 11, s = tok & 2047;
  const float c = cosT[(s << 6) + d];
  const float sn = sinT[(s << 6) + d];
  const size_t src = (size_t)tok * 512 + h * 128 + d;
  const float x0 = bf2f(raw[src]);
  const float x1 = bf2f(raw[src + 64]);
  const size_t db = ((size_t)(b * NKVc + h) * Sc + s) * HDc + d;
  dst[db] = f2bf(x0 * c - x1 * sn);
  dst[db + 64] = f2bf(x1 * c + x0 * sn);
}

// ---------------- causal GQA flash attention (R6: 3-slot ring) --------------
// grid 256 = 32 bh x 8 pairs; 8 waves; Q-tile 128 (16 rows/wave); KV-tile 64.
// Pair p: q-tiles (15-p, p) -> exactly 34 KV iterations. LDS: 3 ring slots
// of 32KB (K 16KB + V 16KB) @0/32768/65536, P per-wave @98304+w*2048.
// Per iter: vmcnt(4) [slot j landed; j+1 in flight] -> barrier -> stage(j+2)
// -> QK^T -> softmax -> P write (wave-local) -> PV -> lgkmcnt(0).
__global__ __launch_bounds__(512, 2) void attn_kernel(const unsigned short* __restrict__ Qraw,
                                                      const unsigned short* __restrict__ Kr,
                                                      const unsigned short* __restrict__ Vt,
                                                      unsigned short* __restrict__ O,
                                                      const float* __restrict__ cosT,
                                                      const float* __restrict__ sinT) {
  __shared__ __align__(16) char smem[114688];

  const int tid = threadIdx.x, w = tid >> 6, l = tid & 63;
  const int g = l >> 4, lc = l & 15;
  const int p = blockIdx.x & 7, bh = blockIdx.x >> 3;
  const int b = bh >> 4, h = bh & 15, kvh = h >> 2;
  const int qt0 = 15 - p, qt1 = p;
  const int L0 = 2 * qt0 + 2;           // iterations in phase 0 (>= 18)
  constexpr int NIT = 34;

  const char* Kb = (const char*)(Kr + (size_t)(b * NKVc + kvh) * Sc * HDc);
  const char* Vb = (const char*)(Vt + (size_t)(b * NKVc + kvh) * HDc * Sc);

  // staging lane constants (512 threads; pre-swizzled global source)
  const int ksr = tid >> 4;                              // K: 32 rows x 256B / issue
  const int kcb = ((tid & 15) * 16) ^ ((ksr & 7) << 4);
  const int vsr = tid >> 3;                              // V: 64 rows x 128B / issue
  const int vcb = ((tid & 7) * 16) ^ ((vsr & 7) << 4);
  char* ldst = smem + tid * 16;

  auto stage = [&](int slot, int kt_) {
    gload_lds16(Kb + (size_t)(kt_ * 64 + ksr) * 256 + kcb, ldst + slot);
    gload_lds16(Kb + (size_t)(kt_ * 64 + 32 + ksr) * 256 + kcb, ldst + slot + 8192);
    gload_lds16(Vb + (size_t)vsr * 4096 + kt_ * 128 + vcb, ldst + slot + 16384);
    gload_lds16(Vb + (size_t)(64 + vsr) * 4096 + kt_ * 128 + vcb, ldst + slot + 24576);
  };

  // swizzled read bases (slot-relative byte offsets)
  const int swb = ((g ^ lc) & 3) * 16 + ((lc >> 2) & 1) * 64;
  const int kbA = lc * 256 + swb;        // + slot + nf*4096 + (kk>>1)*128 (^64 kk odd)
  const int vbA = lc * 128 + swb;        // + slot+16384 + df*2048 (^64 k2 odd)
  const int pwb = 98304 + w * 2048;
  int pwo[8];
#pragma unroll
  for (int r = 0; r < 4; r++)
#pragma unroll
    for (int n1 = 0; n1 < 2; n1++)
      pwo[r * 2 + n1] = pwb + (g * 4 + r) * 128 + (lc & 7) * 2 +
                        16 * (((lc >> 3) & 1) ^ (r & 1)) + 64 * (n1 ^ (g & 1));

  bf16x8 qf[4];
  auto loadQ = [&](int qtl) {
    const int srow = qtl * 128 + w * 16 + lc;
    const unsigned short* Qb = Qraw + ((size_t)(b * Sc + srow) << 11) + h * 128 + (g << 3);
    float x[4][8];
#pragma unroll
    for (int kk = 0; kk < 4; kk++) {
      const bf16x8 v = *reinterpret_cast<const bf16x8*>(Qb + kk * 32);
#pragma unroll
      for (int j = 0; j < 8; j++) x[kk][j] = (float)v[j] * QSCALE;
    }
#pragma unroll
    for (int kk = 0; kk < 2; kk++) {
      const float* cp = cosT + ((size_t)srow << 6) + kk * 32 + (g << 3);
      const float* sp = sinT + ((size_t)srow << 6) + kk * 32 + (g << 3);
      const float4 c0 = *(const float4*)cp, c1 = *(const float4*)(cp + 4);
      const float4 s0 = *(const float4*)sp, s1 = *(const float4*)(sp + 4);
      const float cs[8] = {c0.x, c0.y, c0.z, c0.w, c1.x, c1.y, c1.z, c1.w};
      const float ss[8] = {s0.x, s0.y, s0.z, s0.w, s1.x, s1.y, s1.z, s1.w};
#pragma unroll
      for (int j = 0; j < 8; j++) {
        qf[kk][j] = (__bf16)(x[kk][j] * cs[j] - x[kk + 2][j] * ss[j]);
        qf[kk + 2][j] = (__bf16)(x[kk + 2][j] * cs[j] + x[kk][j] * ss[j]);
      }
    }
  };

  f32x4 zero4 = {0.f, 0.f, 0.f, 0.f};
  f32x4 oacc[8];
#pragma unroll
  for (int i = 0; i < 8; i++) oacc[i] = zero4;
  float mreg[4] = {-1e30f, -1e30f, -1e30f, -1e30f};
  float sume[4] = {0.f, 0.f, 0.f, 0.f};

  int qt = qt0, kt = 0, phase = 0;
  loadQ(qt0);
  stage(0, 0);
  stage(32768, 1);

  auto iter = [&](int i, auto slotc) {
    constexpr int SB = decltype(slotc)::value;       // slot of tile i
    constexpr int SB2 = (SB + 65536) % 98304;        // slot of tile i+2
    if (i < NIT - 2) {
      asm volatile("s_waitcnt vmcnt(4)" ::: "memory");
    } else {
      asm volatile("s_waitcnt vmcnt(0)" ::: "memory");
    }
    __builtin_amdgcn_s_barrier();
    if (i + 2 < NIT) {
      const int kti = i + 2;
      stage(SB2, kti < L0 ? kti : kti - L0);
    }

    // S = Q K^T
    f32x4 sacc[4];
#pragma unroll
    for (int nf = 0; nf < 4; nf++) sacc[nf] = zero4;
    __builtin_amdgcn_s_setprio(1);
#pragma unroll
    for (int nf = 0; nf < 4; nf++) {
#pragma unroll
      for (int kk = 0; kk < 4; kk++) {
        const bf16x8 kf = *reinterpret_cast<const bf16x8*>(
            smem + SB + ((kk & 1) ? (kbA ^ 64) : kbA) + nf * 4096 + (kk >> 1) * 128);
        sacc[nf] = __builtin_amdgcn_mfma_f32_16x16x32_bf16(qf[kk], kf, sacc[nf], 0, 0, 0);
      }
    }
    __builtin_amdgcn_s_setprio(0);

    if (kt >= 2 * qt) {                    // diagonal tiles: causal mask
      const int qrow = (w << 4) + (g << 2) - ((kt - 2 * qt) << 6);
#pragma unroll
      for (int nf = 0; nf < 4; nf++) {
        const int kvl = nf * 16 + lc;
#pragma unroll
        for (int r = 0; r < 4; r++)
          if (kvl > qrow + r) sacc[nf][r] = -1e30f;
      }
    }

    // online softmax with defer-max
    float tmax[4];
#pragma unroll
    for (int r = 0; r < 4; r++) {
      float t = fmaxf(fmaxf(sacc[0][r], sacc[1][r]), fmaxf(sacc[2][r], sacc[3][r]));
#pragma unroll
      for (int m = 1; m < 16; m <<= 1) t = fmaxf(t, __shfl_xor(t, m));
      tmax[r] = t;
    }
    const bool ok = (tmax[0] <= mreg[0] + DEFER_THR) && (tmax[1] <= mreg[1] + DEFER_THR) &&
                    (tmax[2] <= mreg[2] + DEFER_THR) && (tmax[3] <= mreg[3] + DEFER_THR);
    if (!__all(ok)) {
      float alpha[4];
#pragma unroll
      for (int r = 0; r < 4; r++) {
        const float mn = fmaxf(mreg[r], tmax[r]);
        alpha[r] = exp2f(mreg[r] - mn);
        mreg[r] = mn;
        sume[r] *= alpha[r];
      }
#pragma unroll
      for (int i2 = 0; i2 < 8; i2++) {
        f32x4 t = oacc[i2];
        t[0] *= alpha[0]; t[1] *= alpha[1]; t[2] *= alpha[2]; t[3] *= alpha[3];
        oacc[i2] = t;
      }
    }

    // P = exp2(S - m) -> per-wave LDS (imm-offset swizzled)
#pragma unroll
    for (int nf = 0; nf < 4; nf++) {
#pragma unroll
      for (int r = 0; r < 4; r++) {
        const float pv = exp2f(sacc[nf][r] - mreg[r]);
        sume[r] += pv;
        *(unsigned short*)(smem + pwo[r * 2 + (nf >> 1)] +
                           32 * ((nf & 1) ^ ((r >> 1) & 1))) = f2bf(pv);
      }
    }

    // O += P V
    __builtin_amdgcn_s_setprio(1);
#pragma unroll
    for (int k2 = 0; k2 < 2; k2++) {
      const int sb = k2 ? (vbA ^ 64) : vbA;
      const bf16x8 pf = *reinterpret_cast<const bf16x8*>(smem + pwb + (k2 ? (vbA ^ 64) : vbA));
#pragma unroll
      for (int df = 0; df < 8; df++) {
        const bf16x8 vf =
            *reinterpret_cast<const bf16x8*>(smem + SB + 16384 + sb + df * 2048);
        oacc[df] = __builtin_amdgcn_mfma_f32_16x16x32_bf16(pf, vf, oacc[df], 0, 0, 0);
      }
    }
    __builtin_amdgcn_s_setprio(0);

    asm volatile("s_waitcnt lgkmcnt(0)" ::: "memory");   // drain before next barrier

    if (kt == 2 * qt + 1) {                // q-tile finished
      float rinv[4];
#pragma unroll
      for (int r = 0; r < 4; r++) {
        float t = sume[r];
#pragma unroll
        for (int m = 1; m < 16; m <<= 1) t += __shfl_xor(t, m);
        rinv[r] = 1.0f / t;
      }
      unsigned short* Ob = O +
          ((size_t)(b * Sc + qt * 128 + (w << 4) + (g << 2)) * (NHc * HDc)) +
          h * HDc + lc;
#pragma unroll
      for (int df = 0; df < 8; df++)
#pragma unroll
        for (int r = 0; r < 4; r++)
          Ob[(size_t)r * (NHc * HDc) + df * 16] = f2bf(oacc[df][r] * rinv[r]);

      if (phase == 0) {
        phase = 1; qt = qt1; kt = 0;
#pragma unroll
        for (int i2 = 0; i2 < 8; i2++) oacc[i2] = zero4;
#pragma unroll
        for (int r = 0; r < 4; r++) { mreg[r] = -1e30f; sume[r] = 0.f; }
        loadQ(qt1);
      }
    } else {
      kt++;
    }
  };

  int i = 0;
  for (int t3 = 0; t3 < 11; ++t3) {        // 34 = 3*11 + 1
    iter(i, std::integral_constant<int, 0>{}); i++;
    iter(i, std::integral_constant<int, 32768>{}); i++;
    iter(i, std::integral_constant<int, 65536>{}); i++;
  }
  iter(i, std::integral_constant<int, 0>{});
}

// ---------------------------------------------------------------------------
extern "C" void kernel_launch(void* const* d_in, const int* in_sizes, int n_in,
                              void* d_out, int out_size, void* d_ws, size_t ws_size,
                              hipStream_t stream) {
  (void)in_sizes; (void)n_in; (void)out_size; (void)ws_size;
  const float* X = (const float*)d_in[0];
  const float* Wq = (const float*)d_in[1];
  const float* Wk = (const float*)d_in[2];
  const float* Wv = (const float*)d_in[3];
  const float* Wo = (const float*)d_in[4];

  char* ws = (char*)d_ws;
  unsigned short* Xbf  = (unsigned short*)(ws + 0);         // 4096x2048 (16MB)
  unsigned short* Wqkv = (unsigned short*)(ws + 16777216);  // 3072x2048 (12.6MB)
  unsigned short* Wob  = (unsigned short*)(ws + 29360128);  // 2048x2048 (8MB)
  unsigned short* Qraw = (unsigned short*)(ws + 37748736);  // 4096x2048 (16MB)
  unsigned short* Kraw = (unsigned short*)(ws + 54525952);  // 4096x512  (4MB)
  unsigned short* Vt   = (unsigned short*)(ws + 58720256);  // [b][kv][d][s] (4MB)
  float*          cosT = (float*)(ws + 62914560);           // 2048x64 f32 (512KB)
  float*          sinT = (float*)(ws + 63438848);           // 2048x64 f32 (512KB)
  unsigned short* Kr   = (unsigned short*)(ws + 79691776);  // [b][kv][s][d] (4MB)
  unsigned short* Ows  = (unsigned short*)(ws + 83886080);  // 4096x2048 (16MB)

  rope_table<<<512, 256, 0, stream>>>(cosT, sinT);
  cvt_kernel<<<8192, 256, 0, stream>>>(X, Xbf, 2097152);
  cvt_weights<<<10240, 256, 0, stream>>>(Wq, Wk, Wv, Wo, Wqkv, Wob);

  gemm_ring<8, 2><<<192, 512, 0, stream>>>(Xbf, Wqkv, Qraw, Kraw, Vt);

  rope_k<<<4096, 256, 0, stream>>>(Kraw, Kr, cosT, sinT);

  attn_kernel<<<256, 512, 0, stream>>>(Qraw, Kr, Vt, Ows, cosT, sinT);

  gemm_ring<4, 1><<<256, 512, 0, stream>>>(Ows, Wob, d_out, nullptr, nullptr);
}